// Round 3
// baseline (363.432 us; speedup 1.0000x reference)
//
#include <hip/hip_runtime.h>
#include <math.h>

#define G_     128
#define E_     524288
#define EPG    4096
#define DEGMAX 48

typedef __attribute__((ext_vector_type(8))) short bf16x8;
typedef __attribute__((ext_vector_type(4))) float f32x4;
typedef __attribute__((ext_vector_type(4))) unsigned short u16x4;

__device__ inline void split_bf16(float x, short& hi, short& lo){
    unsigned u = __float_as_uint(x);
    hi = (short)(u >> 16);
    float hf = __uint_as_float(u & 0xffff0000u);
    unsigned r = __float_as_uint(x - hf);
    lo = (short)(r >> 16);
}

// ---------------- stage-1 CSR build (padded ushort rows; pads stay 0 from memset) ----------------
__global__ __launch_bounds__(256) void k_build1(const int* __restrict__ ei,
        int* __restrict__ cnt, unsigned short* __restrict__ csrcp){
    int e = blockIdx.x*256 + threadIdx.x;
    int s = ei[e], d = ei[E_ + e];
    int slot = atomicAdd(&cnt[d], 1);
    if (slot < DEGMAX) csrcp[(size_t)d*DEGMAX + slot] = (unsigned short)(s & 511);
}

// ---------------- per-graph feature prop with fused degree prop ----------------
// OUT = dinv * (sum_l A^l)(dinv * X). QUAD (u16x4) gathers, degree counting-sort
// (uniform nq per wave), CSR prefetch.
// R16 re-tile: 512-thread blocks x 16-feature slices (fq=8), y = NPER*16 floats.
// Stage1 LDS 37KB -> 4 blocks x 8 waves per CU (was 2 x 16-wave blocks at 70KB):
// barriers sync 8 waves instead of 16; 3 other blocks fill the CU during drain.
// Global I/O kept coalesced despite sorted thread->vertex assignment by staging
// X and OUT linearly through LDS (sorted access happens in LDS only). This also
// drops the dv[] registers -> helps the hard <=64 VGPR budget for 8 waves/SIMD.
// REGISTER HISTORY (DO NOT REPEAT): min-waves hints that force VGPR below need
// (R7/R14: (1024,8) -> 32 VGPR ceiling) cause catastrophic scratch spill
// (FETCH 20->160MB). Plain launch_bounds; R15 landed exactly 64 VGPR.
template<int NPER, int L, int IT>
__global__ __launch_bounds__(512)
void k_prop(const int* __restrict__ cnt,
        const unsigned short* __restrict__ csrcp,
        const float* __restrict__ X, float* __restrict__ OUT){
    __shared__ __align__(16) float y[NPER*16];
    __shared__ float dinvs[NPER];
    __shared__ int   perm[NPER];      // deg<<16 | local vertex id, ascending by deg
    __shared__ int   bins[64];
    int g = blockIdx.x, fq = blockIdx.y, gbase = g*NPER;
    int t = threadIdx.x;
    int f4 = (t & 3)*4;
    int fo = fq*16 + f4;

    // ---- counting sort of vertices by degree (49 bins, wave-0 shuffle scan) ----
    if (t < 64) bins[t] = 0;
    __syncthreads();
    int dct = 0;
    if (t < NPER){
        dct = min(cnt[gbase + t], DEGMAX);
        atomicAdd(&bins[dct], 1);
    }
    __syncthreads();
    if (t < 64){
        int v0 = bins[t], s = v0;
        #pragma unroll
        for (int off = 1; off < 64; off <<= 1){
            int n = __shfl_up(s, off);
            if (t >= off) s += n;
        }
        bins[t] = s - v0;             // exclusive prefix
    }
    __syncthreads();
    if (t < NPER){
        int slot = atomicAdd(&bins[dct], 1);
        perm[slot] = t | (dct << 16);
    }
    __syncthreads();

    // ---- fused degree prop on sorted assignment (lanes have uniform nq) ----
    int pv = 0, pd = 0;
    if (t < NPER){
        int pk = perm[t];
        pv = pk & 0xffff; pd = pk >> 16;
        y[pv] = 1.f;
    }
    __syncthreads();
    {
        float dacc = 1.f;
        int cur = 0;
        for (int l = 0; l < L; l++){
            if (t < NPER){
                const float* la = &y[cur*NPER];
                float s = 0.f;
                int nq = (pd + 3) >> 2;
                const u16x4* cp = (const u16x4*)(csrcp + (size_t)(gbase + pv)*DEGMAX);
                u16x4 oc = cp[0];
                #pragma unroll 1
                for (int jq = 0; jq < nq; jq++){
                    u16x4 ocn = cp[jq + 1];
                    s += (la[(int)oc[0]] + la[(int)oc[1]]) + (la[(int)oc[2]] + la[(int)oc[3]]);
                    oc = ocn;
                }
                if (nq) s -= (float)(nq*4 - pd) * la[0];
                y[(1^cur)*NPER + pv] = s;
                dacc += s;
            }
            __syncthreads();
            cur ^= 1;
        }
        if (t < NPER) dinvs[pv] = rsqrtf(fmaxf(dacc, 1e-12f));
    }
    __syncthreads();                  // dinvs ready; y region free for staging

    // ---- per-thread sorted vertex assignment: 16 consecutive sorted slots per wave;
    //      odd its flip chunk order so per-wave totals stay balanced at barriers ----
    int pkr[IT];
    {
        int wv = t >> 6, gi = (t >> 2) & 15;
        #pragma unroll
        for (int it = 0; it < IT; it++){
            int ch = (it & 1) ? (7 - wv) : wv;
            pkr[it] = perm[(8*it + ch)*16 + gi];
        }
    }
    // ---- linear (coalesced) X staging into LDS, scaled by dinv ----
    #pragma unroll
    for (int it = 0; it < IT; it++){
        int v = (t >> 2) + 128*it;
        float d = dinvs[v];
        float4 w = *(const float4*)&X[(size_t)(gbase + v)*128 + fo];
        w.x*=d; w.y*=d; w.z*=d; w.w*=d;
        *(float4*)&y[v*16 + f4] = w;
    }
    __syncthreads();
    // ---- acc init: each thread reads its own sorted vertex from LDS ----
    float4 acc[IT];
    #pragma unroll
    for (int it = 0; it < IT; it++){
        int v = pkr[it] & 0xffff;
        acc[it] = *(const float4*)&y[v*16 + f4];
    }
    for (int l = 0; l < L; l++){
        float4 s[IT];
        #pragma unroll
        for (int it = 0; it < IT; it++){
            int pk = pkr[it];
            int c = pk >> 16;
            int nq = (c + 3) >> 2;
            const u16x4* cp = (const u16x4*)(csrcp + (size_t)(gbase + (pk & 0xffff))*DEGMAX);
            float4 ss = make_float4(0.f,0.f,0.f,0.f);
            u16x4 oc = cp[0];
            #pragma unroll 1
            for (int jq = 0; jq < nq; jq++){
                u16x4 ocn = cp[jq + 1];
                float4 w0 = *(const float4*)&y[((int)oc[0])*16 + f4];
                float4 w1 = *(const float4*)&y[((int)oc[1])*16 + f4];
                float4 w2 = *(const float4*)&y[((int)oc[2])*16 + f4];
                float4 w3 = *(const float4*)&y[((int)oc[3])*16 + f4];
                ss.x += (w0.x + w1.x) + (w2.x + w3.x);
                ss.y += (w0.y + w1.y) + (w2.y + w3.y);
                ss.z += (w0.z + w1.z) + (w2.z + w3.z);
                ss.w += (w0.w + w1.w) + (w2.w + w3.w);
                oc = ocn;
            }
            if (nq){
                float fp = (float)(nq*4 - c);
                float4 z = *(const float4*)&y[f4];          // row 0
                ss.x -= fp*z.x; ss.y -= fp*z.y; ss.z -= fp*z.z; ss.w -= fp*z.w;
            }
            s[it] = ss;
        }
        __syncthreads();
        #pragma unroll
        for (int it = 0; it < IT; it++){
            int v = pkr[it] & 0xffff;
            *(float4*)&y[v*16 + f4] = s[it];
            acc[it].x+=s[it].x; acc[it].y+=s[it].y; acc[it].z+=s[it].z; acc[it].w+=s[it].w;
        }
        __syncthreads();
    }
    // ---- stage acc back to LDS (scattered LDS write), then linear OUT store ----
    #pragma unroll
    for (int it = 0; it < IT; it++){
        int v = pkr[it] & 0xffff;
        *(float4*)&y[v*16 + f4] = acc[it];
    }
    __syncthreads();
    #pragma unroll
    for (int it = 0; it < IT; it++){
        int v = (t >> 2) + 128*it;
        float d = dinvs[v];
        float4 w = *(const float4*)&y[v*16 + f4];
        w.x*=d; w.y*=d; w.z*=d; w.w*=d;
        *(float4*)&OUT[(size_t)(gbase + v)*128 + fo] = w;
    }
}

// ---------------- split-bf16 MFMA GEMM: Y = X(Mx128) @ W(128x128) + bias ----------------
// W (hi/lo) staged once in LDS; A loaded straight to registers (no cross-wave A reuse).
// Big GEMMs at RT=2 -> 512 blocks = 2 blocks/CU for latency hiding.
template<int RT>
__global__ __launch_bounds__(256) void k_gemm_mfma(const float* __restrict__ X,
        const float* __restrict__ W, const float* __restrict__ bias, float* __restrict__ Y){
    __shared__ short wsh[128*136];
    __shared__ short wsl[128*136];
    __shared__ float bsh[128];
    int t = threadIdx.x;
    for (int e = t; e < 16384; e += 256){
        int k = e >> 7, n = e & 127;
        short hi, lo; split_bf16(W[e], hi, lo);
        wsh[n*136 + k] = hi; wsl[n*136 + k] = lo;
    }
    if (t < 128) bsh[t] = bias[t];
    __syncthreads();
    int wave = t >> 6, lane = t & 63;
    int ln = lane & 15, q = lane >> 4;
    size_t rb0 = (size_t)blockIdx.x * (64*RT);
    for (int rt = 0; rt < RT; rt++){
        size_t rb = rb0 + (size_t)rt*64;
        const float* xrow = &X[(rb + wave*16 + ln)*128 + q*8];
        f32x4 acc[8];
        #pragma unroll
        for (int i = 0; i < 8; i++) acc[i] = (f32x4){0.f,0.f,0.f,0.f};
        #pragma unroll
        for (int kc = 0; kc < 4; kc++){
            float4 xa = *(const float4*)(xrow + kc*32);
            float4 xb = *(const float4*)(xrow + kc*32 + 4);
            bf16x8 ah, al; short hi, lo;
            split_bf16(xa.x, hi, lo); ah[0]=hi; al[0]=lo;
            split_bf16(xa.y, hi, lo); ah[1]=hi; al[1]=lo;
            split_bf16(xa.z, hi, lo); ah[2]=hi; al[2]=lo;
            split_bf16(xa.w, hi, lo); ah[3]=hi; al[3]=lo;
            split_bf16(xb.x, hi, lo); ah[4]=hi; al[4]=lo;
            split_bf16(xb.y, hi, lo); ah[5]=hi; al[5]=lo;
            split_bf16(xb.z, hi, lo); ah[6]=hi; al[6]=lo;
            split_bf16(xb.w, hi, lo); ah[7]=hi; al[7]=lo;
            #pragma unroll
            for (int nt = 0; nt < 8; nt++){
                int wo = (nt*16 + ln)*136 + kc*32 + q*8;
                bf16x8 bh = *(const bf16x8*)&wsh[wo];
                bf16x8 bl = *(const bf16x8*)&wsl[wo];
                acc[nt] = __builtin_amdgcn_mfma_f32_16x16x32_bf16(ah, bh, acc[nt], 0, 0, 0);
                acc[nt] = __builtin_amdgcn_mfma_f32_16x16x32_bf16(ah, bl, acc[nt], 0, 0, 0);
                acc[nt] = __builtin_amdgcn_mfma_f32_16x16x32_bf16(al, bh, acc[nt], 0, 0, 0);
            }
        }
        #pragma unroll
        for (int nt = 0; nt < 8; nt++){
            int c = nt*16 + ln;
            float bb = bsh[c];
            #pragma unroll
            for (int r = 0; r < 4; r++){
                Y[(rb + wave*16 + q*4 + r)*128 + c] = acc[nt][r] + bb;
            }
        }
    }
}

// ---------------- fused pooling: score + top-k + scatter + edge remap + next CSR build ----------------
// R16: rank loop vectorized (float4 broadcast reads, unroll 8) -- was 512 dependent
// scalar LDS reads per thread (~120cy latency each if not pipelined).
template<int NPER, bool BUILD>
__global__ __launch_bounds__(512) void k_pooltop(const float* __restrict__ h, const float* __restrict__ p,
        const float* __restrict__ beta, const int* __restrict__ cnt,
        const int* __restrict__ esrc_in, const int* __restrict__ edst_in,
        int* __restrict__ esrc_out, int* __restrict__ edst_out,
        int* __restrict__ cnt_next, unsigned short* __restrict__ csrcp,
        float* __restrict__ hout, int mask){
    __shared__ __align__(16) float q[128];
    __shared__ __align__(16) float sc[NPER];
    __shared__ float th[NPER];
    __shared__ int  nid[NPER];
    __shared__ float red[64];
    const int K = NPER/2;
    int g = blockIdx.x, t = threadIdx.x, gbase = g*NPER;
    float b0 = beta[0], b1 = beta[1];
    if (BUILD && t < K) cnt_next[g*K + t] = 0;
    if (t < 64){ float a = p[t], b = p[t+64]; red[t] = a*a + b*b; }
    __syncthreads();
    if (t == 0){ float s = 0.f; for (int i = 0; i < 64; i++) s += red[i]; red[0] = sqrtf(s); }
    __syncthreads();
    if (t < 128) q[t] = b0 * p[t] / red[0];
    __syncthreads();
    if (t < NPER){
        const float4* hr = (const float4*)(h + (size_t)(gbase + t)*128);
        const float4* q4 = (const float4*)q;
        float s = 0.f;
        #pragma unroll 8
        for (int j = 0; j < 32; j++){
            float4 a = hr[j], b = q4[j];
            s += a.x*b.x + a.y*b.y + a.z*b.z + a.w*b.w;
        }
        s += b1 * (float)cnt[gbase + t];
        sc[t] = s;
    }
    __syncthreads();
    if (t < NPER){
        float s = sc[t];
        int rank = 0;
        const float4* sc4 = (const float4*)sc;
        #pragma unroll 8
        for (int j4 = 0; j4 < NPER/4; j4++){
            float4 v = sc4[j4];
            int j = j4*4;
            rank += (v.x > s) || (v.x == s && (j+0) < t);   // stable tie-break = lax.top_k
            rank += (v.y > s) || (v.y == s && (j+1) < t);
            rank += (v.z > s) || (v.z == s && (j+2) < t);
            rank += (v.w > s) || (v.w == s && (j+3) < t);
        }
        nid[t] = (rank < K) ? (g*K + rank) : -1;
        th[t] = tanhf(s);
    }
    __syncthreads();
    for (int base = t; base < NPER*32; base += 512){
        int v = base >> 5, f4 = base & 31;
        int ni = nid[v];
        if (ni >= 0){
            float tt = th[v];
            float4 w = *(const float4*)&h[(size_t)(gbase + v)*128 + f4*4];
            w.x*=tt; w.y*=tt; w.z*=tt; w.w*=tt;
            *(float4*)&hout[(size_t)ni*128 + f4*4] = w;
        }
    }
    if (BUILD){
        for (int i = t; i < EPG; i += 512){
            int e = g*EPG + i;
            int d = edst_in[e];
            if (d < 0) continue;
            int s_ = esrc_in[e];
            int ns = nid[s_ - gbase], nd = nid[d - gbase];
            if ((ns | nd) < 0){ edst_out[e] = -1; }
            else {
                esrc_out[e] = ns; edst_out[e] = nd;
                int slot = atomicAdd(&cnt_next[nd], 1);
                if (slot < DEGMAX) csrcp[(size_t)nd*DEGMAX + slot] = (unsigned short)(ns & mask);
            }
        }
    }
}

// ---------------- fused readout: scatter-mean + 2-layer MLP ----------------
__global__ __launch_bounds__(128) void k_meanmlp(const float* __restrict__ h, const float* __restrict__ W1,
        const float* __restrict__ b1, const float* __restrict__ W2, const float* __restrict__ b2,
        float* __restrict__ out){
    __shared__ float mr[128];
    int g = blockIdx.x, t = threadIdx.x;
    float s = 0.f;
    #pragma unroll 8
    for (int r = 0; r < 64; r++) s += h[((size_t)g*64 + r)*128 + t];
    mr[t] = s * (1.f/64.f);
    __syncthreads();
    if (t < 64){
        float a = b1[t];
        #pragma unroll 8
        for (int k = 0; k < 128; k++) a += mr[k]*W1[k*64 + t];
        a = fmaxf(a, 0.f);
        float r = a * W2[t];
        #pragma unroll
        for (int off = 32; off > 0; off >>= 1) r += __shfl_down(r, off);
        if (t == 0) out[g] = r + b2[0];
    }
}

// ---------------- driver ----------------
extern "C" void kernel_launch(void* const* d_in, const int* in_sizes, int n_in,
                              void* d_out, int out_size, void* d_ws, size_t ws_size,
                              hipStream_t stream){
    (void)in_sizes; (void)n_in; (void)out_size; (void)ws_size;
    const float* x     = (const float*)d_in[0];
    const int*   ei    = (const int*)d_in[1];
    const float* lumpW = (const float*)d_in[3];
    const float* lumpb = (const float*)d_in[4];
    const float* convW[3]    = {(const float*)d_in[5], (const float*)d_in[7], (const float*)d_in[9]};
    const float* convB[3]    = {(const float*)d_in[6], (const float*)d_in[8], (const float*)d_in[10]};
    const float* poolP[3]    = {(const float*)d_in[11], (const float*)d_in[13], (const float*)d_in[15]};
    const float* poolBeta[3] = {(const float*)d_in[12], (const float*)d_in[14], (const float*)d_in[16]};
    const float* lin1W = (const float*)d_in[17];
    const float* lin1b = (const float*)d_in[18];
    const float* lin2W = (const float*)d_in[19];
    const float* lin2b = (const float*)d_in[20];
    float* out = (float*)d_out;

    char* w8 = (char*)d_ws;
    size_t off = 0;
    auto alloc = [&](size_t bytes)->char*{
        char* p = w8 + off; off += (bytes + 255) & ~(size_t)255; return p;
    };
    float* A     = (float*)alloc((size_t)65536*128*4);
    float* Bb    = (float*)alloc((size_t)65536*128*4);
    float* Cc    = (float*)alloc((size_t)32768*128*4);
    int*   srcA  = (int*)alloc((size_t)E_*4);
    int*   dstA  = (int*)alloc((size_t)E_*4);
    // csr1/csr2/csr3 + cnt1 contiguous: one memset zeroes rows (pad slots must be 0)
    unsigned short* csr1 = (unsigned short*)alloc((size_t)65536*DEGMAX*2);
    unsigned short* csr2 = (unsigned short*)alloc((size_t)32768*DEGMAX*2);
    unsigned short* csr3 = (unsigned short*)alloc((size_t)16384*DEGMAX*2);
    int*   cntA  = (int*)alloc((size_t)(65536+32768+16384)*4);
    int*   cnt1 = cntA, *cnt2 = cntA + 65536, *cnt3 = cntA + 98304;

    dim3 b256(256);

    size_t zbytes = (size_t)(65536+32768+16384)*DEGMAX*2 + (size_t)65536*4;
    hipMemsetAsync(csr1, 0, zbytes, stream);
    k_gemm_mfma<2><<<512, b256, 0, stream>>>(x, lumpW, lumpb, A);
    k_build1<<<E_/256, b256, 0, stream>>>(ei, cnt1, csr1);

    // ----- stage 1: conv1 (L=4, nper=512), pool -> 256/graph -----
    k_prop<512,4,4><<<dim3(G_,8), 512, 0, stream>>>(cnt1, csr1, A, Bb);
    k_gemm_mfma<2><<<512, b256, 0, stream>>>(Bb, convW[0], convB[0], A);
    k_pooltop<512,true><<<G_, 512, 0, stream>>>(A, poolP[0], poolBeta[0], cnt1,
            ei, ei + E_, srcA, dstA, cnt2, csr2, Cc, 255);

    // ----- stage 2: conv2 (L=2, nper=256), pool -> 128/graph -----
    k_prop<256,2,2><<<dim3(G_,8), 512, 0, stream>>>(cnt2, csr2, Cc, Bb);
    k_gemm_mfma<1><<<512, b256, 0, stream>>>(Bb, convW[1], convB[1], A);
    k_pooltop<256,true><<<G_, 512, 0, stream>>>(A, poolP[1], poolBeta[1], cnt2,
            srcA, dstA, srcA, dstA, cnt3, csr3, Cc, 127);

    // ----- stage 3: conv3 (L=2, nper=128), pool -> 64/graph -----
    k_prop<128,2,1><<<dim3(G_,8), 512, 0, stream>>>(cnt3, csr3, Cc, Bb);
    k_gemm_mfma<1><<<256, b256, 0, stream>>>(Bb, convW[2], convB[2], A);
    k_pooltop<128,false><<<G_, 512, 0, stream>>>(A, poolP[2], poolBeta[2], cnt3,
            nullptr, nullptr, nullptr, nullptr, nullptr, nullptr, Cc, 0);

    // ----- readout -----
    k_meanmlp<<<G_, 128, 0, stream>>>(Cc, lin1W, lin1b, lin2W, lin2b, out);
}

// Round 4
// 341.622 us; speedup vs baseline: 1.0638x; 1.0638x over previous
//
#include <hip/hip_runtime.h>
#include <math.h>

#define G_     128
#define E_     524288
#define EPG    4096
#define DEGMAX 48

typedef __attribute__((ext_vector_type(8))) short bf16x8;
typedef __attribute__((ext_vector_type(4))) float f32x4;
typedef __attribute__((ext_vector_type(4))) unsigned short u16x4;

__device__ inline void split_bf16(float x, short& hi, short& lo){
    unsigned u = __float_as_uint(x);
    hi = (short)(u >> 16);
    float hf = __uint_as_float(u & 0xffff0000u);
    unsigned r = __float_as_uint(x - hf);
    lo = (short)(r >> 16);
}

// ---------------- stage-1 prep: CSR build + count + degree-sort + degree-prop + dinv ----------------
// Replaces k_build1 (524K global atomics, ~8-way contention) with per-graph LDS
// counters, and hoists the sort + L-level degree propagation that every k_prop
// block redundantly recomputed (4x per graph, with half its threads idle).
__global__ __launch_bounds__(512) void k_prep1(const int* __restrict__ ei,
        int* __restrict__ cnt, unsigned short* __restrict__ csrcp,
        int* __restrict__ permg, float* __restrict__ dinvg){
    __shared__ int   lcnt[512];
    __shared__ float y[1024];          // degree ping-pong
    __shared__ int   bins[64];
    __shared__ int   permS[512];
    int g = blockIdx.x, t = threadIdx.x, gbase = g*512;
    lcnt[t] = 0;
    if (t < 64) bins[t] = 0;
    __syncthreads();
    for (int i = t; i < EPG; i += 512){
        int e = g*EPG + i;
        int sv = ei[e] & 511;          // ids are g*512+local; 512-aligned -> &511 = local
        int d  = ei[E_ + e] & 511;
        int slot = atomicAdd(&lcnt[d], 1);
        if (slot < DEGMAX) csrcp[(size_t)(gbase + d)*DEGMAX + slot] = (unsigned short)sv;
    }
    __syncthreads();                   // csr (global, own block) + lcnt ready
    int rawc = lcnt[t];
    cnt[gbase + t] = rawc;             // pooltop's node-strength term (unclamped)
    int dc = min(rawc, DEGMAX);
    atomicAdd(&bins[dc], 1);
    __syncthreads();
    if (t < 64){
        int v0 = bins[t], s = v0;
        #pragma unroll
        for (int off = 1; off < 64; off <<= 1){
            int n = __shfl_up(s, off);
            if (t >= off) s += n;
        }
        bins[t] = s - v0;              // exclusive prefix
    }
    __syncthreads();
    {
        int slot = atomicAdd(&bins[dc], 1);
        int pk = t | (dc << 16);
        permS[slot] = pk;
        permg[gbase + slot] = pk;
    }
    __syncthreads();
    int pk = permS[t];
    int pv = pk & 0xffff, pd = pk >> 16;
    y[pv] = 1.f;
    __syncthreads();
    float dacc = 1.f;
    int cur = 0;
    for (int l = 0; l < 4; l++){
        const float* la = &y[cur*512];
        float s = 0.f;
        int nq = (pd + 3) >> 2;
        const u16x4* cp = (const u16x4*)(csrcp + (size_t)(gbase + pv)*DEGMAX);
        u16x4 oc = cp[0];
        #pragma unroll 1
        for (int jq = 0; jq < nq; jq++){
            u16x4 ocn = cp[jq + 1];    // +8B over-read stays in workspace
            s += (la[(int)oc[0]] + la[(int)oc[1]]) + (la[(int)oc[2]] + la[(int)oc[3]]);
            oc = ocn;
        }
        if (nq) s -= (float)(nq*4 - pd) * la[0];
        y[(1^cur)*512 + pv] = s;       // other buffer: no hazard, 1 barrier/level
        dacc += s;
        __syncthreads();
        cur ^= 1;
    }
    dinvg[gbase + pv] = rsqrtf(fmaxf(dacc, 1e-12f));
}

// ---------------- per-graph feature prop ----------------
// OUT = dinv * (sum_l A^l)(dinv * X). R15 tiling (1024 thr, fq=4, 128B row stride:
// measured balanced at the b128 issue floor; R16's 64B stride DOUBLED conflicts).
// Sort + degree-prop hoisted to prep/pooltop -> this kernel only does the feature
// gather. perm/dinv come from global.
// REGISTER HISTORY (DO NOT REPEAT): min-waves hints (R7/R14 launch_bounds(1024,8))
// force a 32-VGPR ceiling -> catastrophic scratch spill (FETCH 20->160MB).
template<int NPER, int L, int IT>
__global__ __launch_bounds__(1024)
void k_prop(const int* __restrict__ permg, const float* __restrict__ dinvg,
        const unsigned short* __restrict__ csrcp,
        const float* __restrict__ X, float* __restrict__ OUT){
    __shared__ __align__(16) float y[NPER*32];
    __shared__ float dinvs[NPER];
    int g = blockIdx.x, fq = blockIdx.y, gbase = g*NPER;
    int t = threadIdx.x;
    int f4 = (t & 7)*4;
    int fo = fq*32 + f4;
    if (t < NPER) dinvs[t] = dinvg[gbase + t];
    // sorted slots: 8 consecutive per wave-group; odd its flip chunk order to
    // balance per-wave totals at the level barriers
    int pkr[IT];
    {
        int wv = t >> 6, gi = (t >> 3) & 7;
        #pragma unroll
        for (int it = 0; it < IT; it++){
            int ch = (it & 1) ? (15 - wv) : wv;
            pkr[it] = permg[gbase + (16*it + ch)*8 + gi];
        }
    }
    __syncthreads();
    float4 acc[IT];
    #pragma unroll
    for (int it = 0; it < IT; it++){
        int v = pkr[it] & 0xffff;
        float d = dinvs[v];
        float4 w = *(const float4*)&X[(size_t)(gbase + v)*128 + fo];
        w.x*=d; w.y*=d; w.z*=d; w.w*=d;
        acc[it] = w;
        *(float4*)&y[v*32 + f4] = w;
    }
    __syncthreads();
    for (int l = 0; l < L; l++){
        float4 s[IT];
        #pragma unroll
        for (int it = 0; it < IT; it++){
            int pk = pkr[it];
            int c = pk >> 16;
            int nq = (c + 3) >> 2;
            const u16x4* cp = (const u16x4*)(csrcp + (size_t)(gbase + (pk & 0xffff))*DEGMAX);
            float4 ss = make_float4(0.f,0.f,0.f,0.f);
            u16x4 oc = cp[0];
            #pragma unroll 1
            for (int jq = 0; jq < nq; jq++){
                u16x4 ocn = cp[jq + 1];
                float4 w0 = *(const float4*)&y[((int)oc[0])*32 + f4];
                float4 w1 = *(const float4*)&y[((int)oc[1])*32 + f4];
                float4 w2 = *(const float4*)&y[((int)oc[2])*32 + f4];
                float4 w3 = *(const float4*)&y[((int)oc[3])*32 + f4];
                ss.x += (w0.x + w1.x) + (w2.x + w3.x);
                ss.y += (w0.y + w1.y) + (w2.y + w3.y);
                ss.z += (w0.z + w1.z) + (w2.z + w3.z);
                ss.w += (w0.w + w1.w) + (w2.w + w3.w);
                oc = ocn;
            }
            if (nq){
                float fp = (float)(nq*4 - c);
                float4 z = *(const float4*)&y[f4];          // row 0 (broadcast)
                ss.x -= fp*z.x; ss.y -= fp*z.y; ss.z -= fp*z.z; ss.w -= fp*z.w;
            }
            s[it] = ss;
        }
        __syncthreads();
        #pragma unroll
        for (int it = 0; it < IT; it++){
            int v = pkr[it] & 0xffff;
            *(float4*)&y[v*32 + f4] = s[it];
            acc[it].x+=s[it].x; acc[it].y+=s[it].y; acc[it].z+=s[it].z; acc[it].w+=s[it].w;
        }
        __syncthreads();
    }
    #pragma unroll
    for (int it = 0; it < IT; it++){
        int v = pkr[it] & 0xffff;
        float d = dinvs[v];
        float4 w = acc[it];
        w.x*=d; w.y*=d; w.z*=d; w.w*=d;
        *(float4*)&OUT[(size_t)(gbase + v)*128 + fo] = w;
    }
}

// ---------------- split-bf16 MFMA GEMM: Y = X(Mx128) @ W(128x128) + bias ----------------
template<int RT>
__global__ __launch_bounds__(256) void k_gemm_mfma(const float* __restrict__ X,
        const float* __restrict__ W, const float* __restrict__ bias, float* __restrict__ Y){
    __shared__ short wsh[128*136];
    __shared__ short wsl[128*136];
    __shared__ float bsh[128];
    int t = threadIdx.x;
    for (int e = t; e < 16384; e += 256){
        int k = e >> 7, n = e & 127;
        short hi, lo; split_bf16(W[e], hi, lo);
        wsh[n*136 + k] = hi; wsl[n*136 + k] = lo;
    }
    if (t < 128) bsh[t] = bias[t];
    __syncthreads();
    int wave = t >> 6, lane = t & 63;
    int ln = lane & 15, q = lane >> 4;
    size_t rb0 = (size_t)blockIdx.x * (64*RT);
    for (int rt = 0; rt < RT; rt++){
        size_t rb = rb0 + (size_t)rt*64;
        const float* xrow = &X[(rb + wave*16 + ln)*128 + q*8];
        f32x4 acc[8];
        #pragma unroll
        for (int i = 0; i < 8; i++) acc[i] = (f32x4){0.f,0.f,0.f,0.f};
        #pragma unroll
        for (int kc = 0; kc < 4; kc++){
            float4 xa = *(const float4*)(xrow + kc*32);
            float4 xb = *(const float4*)(xrow + kc*32 + 4);
            bf16x8 ah, al; short hi, lo;
            split_bf16(xa.x, hi, lo); ah[0]=hi; al[0]=lo;
            split_bf16(xa.y, hi, lo); ah[1]=hi; al[1]=lo;
            split_bf16(xa.z, hi, lo); ah[2]=hi; al[2]=lo;
            split_bf16(xa.w, hi, lo); ah[3]=hi; al[3]=lo;
            split_bf16(xb.x, hi, lo); ah[4]=hi; al[4]=lo;
            split_bf16(xb.y, hi, lo); ah[5]=hi; al[5]=lo;
            split_bf16(xb.z, hi, lo); ah[6]=hi; al[6]=lo;
            split_bf16(xb.w, hi, lo); ah[7]=hi; al[7]=lo;
            #pragma unroll
            for (int nt = 0; nt < 8; nt++){
                int wo = (nt*16 + ln)*136 + kc*32 + q*8;
                bf16x8 bh = *(const bf16x8*)&wsh[wo];
                bf16x8 bl = *(const bf16x8*)&wsl[wo];
                acc[nt] = __builtin_amdgcn_mfma_f32_16x16x32_bf16(ah, bh, acc[nt], 0, 0, 0);
                acc[nt] = __builtin_amdgcn_mfma_f32_16x16x32_bf16(ah, bl, acc[nt], 0, 0, 0);
                acc[nt] = __builtin_amdgcn_mfma_f32_16x16x32_bf16(al, bh, acc[nt], 0, 0, 0);
            }
        }
        #pragma unroll
        for (int nt = 0; nt < 8; nt++){
            int c = nt*16 + ln;
            float bb = bsh[c];
            #pragma unroll
            for (int r = 0; r < 4; r++){
                Y[(rb + wave*16 + q*4 + r)*128 + c] = acc[nt][r] + bb;
            }
        }
    }
}

// ---------------- fused pooling: score + top-k + scatter + edge remap + NEXT-stage prep ----------------
// BUILD: cnt_next atomics localized to LDS (all block-local); next-stage CSR built,
// then the next stage's degree-sort + L=2 degree-prop + dinv computed in the tail
// (CSR just written by this block -> L1/L2 hot, __syncthreads orders global writes).
template<int NPER, bool BUILD>
__global__ __launch_bounds__(512) void k_pooltop(const float* __restrict__ h, const float* __restrict__ p,
        const float* __restrict__ beta, const int* __restrict__ cnt,
        const int* __restrict__ esrc_in, const int* __restrict__ edst_in,
        int* __restrict__ esrc_out, int* __restrict__ edst_out,
        int* __restrict__ cnt_next, unsigned short* __restrict__ csrcp,
        int* __restrict__ permg, float* __restrict__ dinvg,
        float* __restrict__ hout){
    __shared__ __align__(16) float q[128];
    __shared__ __align__(16) float sc[NPER];
    __shared__ float th[NPER];
    __shared__ int  nid[NPER];
    __shared__ float red[64];
    __shared__ int  lcnt[NPER/2];
    __shared__ int  bins[64];
    __shared__ int  permS[NPER/2];
    const int K = NPER/2;
    int g = blockIdx.x, t = threadIdx.x, gbase = g*NPER;
    float b0 = beta[0], b1 = beta[1];
    if (BUILD && t < K) lcnt[t] = 0;
    if (t < 64) bins[t] = 0;
    if (t < 64){ float a = p[t], b = p[t+64]; red[t] = a*a + b*b; }
    __syncthreads();
    if (t == 0){ float s = 0.f; for (int i = 0; i < 64; i++) s += red[i]; red[0] = sqrtf(s); }
    __syncthreads();
    if (t < 128) q[t] = b0 * p[t] / red[0];
    __syncthreads();
    if (t < NPER){
        const float4* hr = (const float4*)(h + (size_t)(gbase + t)*128);
        const float4* q4 = (const float4*)q;
        float s = 0.f;
        #pragma unroll 8
        for (int j = 0; j < 32; j++){
            float4 a = hr[j], b = q4[j];
            s += a.x*b.x + a.y*b.y + a.z*b.z + a.w*b.w;
        }
        s += b1 * (float)cnt[gbase + t];
        sc[t] = s;
    }
    __syncthreads();
    if (t < NPER){
        float s = sc[t];
        int rank = 0;
        const float4* sc4 = (const float4*)sc;
        #pragma unroll 8
        for (int j4 = 0; j4 < NPER/4; j4++){
            float4 v = sc4[j4];
            int j = j4*4;
            rank += (v.x > s) || (v.x == s && (j+0) < t);   // stable tie-break = lax.top_k
            rank += (v.y > s) || (v.y == s && (j+1) < t);
            rank += (v.z > s) || (v.z == s && (j+2) < t);
            rank += (v.w > s) || (v.w == s && (j+3) < t);
        }
        nid[t] = (rank < K) ? (g*K + rank) : -1;
        th[t] = tanhf(s);
    }
    __syncthreads();
    for (int base = t; base < NPER*32; base += 512){
        int v = base >> 5, f4 = base & 31;
        int ni = nid[v];
        if (ni >= 0){
            float tt = th[v];
            float4 w = *(const float4*)&h[(size_t)(gbase + v)*128 + f4*4];
            w.x*=tt; w.y*=tt; w.z*=tt; w.w*=tt;
            *(float4*)&hout[(size_t)ni*128 + f4*4] = w;
        }
    }
    if (BUILD){
        for (int i = t; i < EPG; i += 512){
            int e = g*EPG + i;
            int d = edst_in[e];
            if (d < 0) continue;
            int s_ = esrc_in[e];
            int ns = nid[s_ - gbase], nd = nid[d - gbase];
            if ((ns | nd) < 0){ edst_out[e] = -1; }
            else {
                esrc_out[e] = ns; edst_out[e] = nd;
                int slot = atomicAdd(&lcnt[nd & (K-1)], 1);
                if (slot < DEGMAX) csrcp[(size_t)nd*DEGMAX + slot] = (unsigned short)(ns & (K-1));
            }
        }
        __syncthreads();               // csr (global, own block) + lcnt ready
        float* yd = sc;                // reuse: sc dead after rank; 2*K == NPER floats
        int rawc = 0, dc = 0;
        if (t < K){
            rawc = lcnt[t];
            cnt_next[g*K + t] = rawc;
            dc = min(rawc, DEGMAX);
            atomicAdd(&bins[dc], 1);
        }
        __syncthreads();
        if (t < 64){
            int v0 = bins[t], s = v0;
            #pragma unroll
            for (int off = 1; off < 64; off <<= 1){
                int n = __shfl_up(s, off);
                if (t >= off) s += n;
            }
            bins[t] = s - v0;
        }
        __syncthreads();
        if (t < K){
            int slot = atomicAdd(&bins[dc], 1);
            permS[slot] = t | (dc << 16);
            permg[g*K + slot] = permS[slot];
        }
        __syncthreads();
        int pv = 0, pd = 0;
        if (t < K){
            int pk = permS[t];
            pv = pk & 0xffff; pd = pk >> 16;
            yd[pv] = 1.f;
        }
        __syncthreads();
        float dacc = 1.f;
        int cur = 0;
        for (int l = 0; l < 2; l++){
            if (t < K){
                const float* la = &yd[cur*K];
                float s = 0.f;
                int nq = (pd + 3) >> 2;
                const u16x4* cp = (const u16x4*)(csrcp + (size_t)(g*K + pv)*DEGMAX);
                u16x4 oc = cp[0];
                #pragma unroll 1
                for (int jq = 0; jq < nq; jq++){
                    u16x4 ocn = cp[jq + 1];
                    s += (la[(int)oc[0]] + la[(int)oc[1]]) + (la[(int)oc[2]] + la[(int)oc[3]]);
                    oc = ocn;
                }
                if (nq) s -= (float)(nq*4 - pd) * la[0];
                yd[(1^cur)*K + pv] = s;
                dacc += s;
            }
            __syncthreads();
            cur ^= 1;
        }
        if (t < K) dinvg[g*K + pv] = rsqrtf(fmaxf(dacc, 1e-12f));
    }
}

// ---------------- fused readout: scatter-mean + 2-layer MLP ----------------
__global__ __launch_bounds__(128) void k_meanmlp(const float* __restrict__ h, const float* __restrict__ W1,
        const float* __restrict__ b1, const float* __restrict__ W2, const float* __restrict__ b2,
        float* __restrict__ out){
    __shared__ float mr[128];
    int g = blockIdx.x, t = threadIdx.x;
    float s = 0.f;
    #pragma unroll 8
    for (int r = 0; r < 64; r++) s += h[((size_t)g*64 + r)*128 + t];
    mr[t] = s * (1.f/64.f);
    __syncthreads();
    if (t < 64){
        float a = b1[t];
        #pragma unroll 8
        for (int k = 0; k < 128; k++) a += mr[k]*W1[k*64 + t];
        a = fmaxf(a, 0.f);
        float r = a * W2[t];
        #pragma unroll
        for (int off = 32; off > 0; off >>= 1) r += __shfl_down(r, off);
        if (t == 0) out[g] = r + b2[0];
    }
}

// ---------------- driver ----------------
extern "C" void kernel_launch(void* const* d_in, const int* in_sizes, int n_in,
                              void* d_out, int out_size, void* d_ws, size_t ws_size,
                              hipStream_t stream){
    (void)in_sizes; (void)n_in; (void)out_size; (void)ws_size;
    const float* x     = (const float*)d_in[0];
    const int*   ei    = (const int*)d_in[1];
    const float* lumpW = (const float*)d_in[3];
    const float* lumpb = (const float*)d_in[4];
    const float* convW[3]    = {(const float*)d_in[5], (const float*)d_in[7], (const float*)d_in[9]};
    const float* convB[3]    = {(const float*)d_in[6], (const float*)d_in[8], (const float*)d_in[10]};
    const float* poolP[3]    = {(const float*)d_in[11], (const float*)d_in[13], (const float*)d_in[15]};
    const float* poolBeta[3] = {(const float*)d_in[12], (const float*)d_in[14], (const float*)d_in[16]};
    const float* lin1W = (const float*)d_in[17];
    const float* lin1b = (const float*)d_in[18];
    const float* lin2W = (const float*)d_in[19];
    const float* lin2b = (const float*)d_in[20];
    float* out = (float*)d_out;

    char* w8 = (char*)d_ws;
    size_t off = 0;
    auto alloc = [&](size_t bytes)->char*{
        char* p = w8 + off; off += (bytes + 255) & ~(size_t)255; return p;
    };
    float* A     = (float*)alloc((size_t)65536*128*4);
    float* Bb    = (float*)alloc((size_t)65536*128*4);
    float* Cc    = (float*)alloc((size_t)32768*128*4);
    int*   srcA  = (int*)alloc((size_t)E_*4);
    int*   dstA  = (int*)alloc((size_t)E_*4);
    // csr1/csr2/csr3 contiguous: one memset zeroes pad slots
    unsigned short* csr1 = (unsigned short*)alloc((size_t)65536*DEGMAX*2);
    unsigned short* csr2 = (unsigned short*)alloc((size_t)32768*DEGMAX*2);
    unsigned short* csr3 = (unsigned short*)alloc((size_t)16384*DEGMAX*2);
    int*   cntA  = (int*)alloc((size_t)(65536+32768+16384)*4);
    int*   cnt1 = cntA, *cnt2 = cntA + 65536, *cnt3 = cntA + 98304;
    int*   perm1 = (int*)alloc((size_t)65536*4);
    int*   perm2 = (int*)alloc((size_t)32768*4);
    int*   perm3 = (int*)alloc((size_t)16384*4);
    float* dinv1 = (float*)alloc((size_t)65536*4);
    float* dinv2 = (float*)alloc((size_t)32768*4);
    float* dinv3 = (float*)alloc((size_t)16384*4);

    dim3 b256(256);

    size_t zbytes = (size_t)(65536+32768+16384)*DEGMAX*2;
    hipMemsetAsync(csr1, 0, zbytes, stream);
    k_gemm_mfma<2><<<512, b256, 0, stream>>>(x, lumpW, lumpb, A);
    k_prep1<<<G_, 512, 0, stream>>>(ei, cnt1, csr1, perm1, dinv1);

    // ----- stage 1: conv1 (L=4, nper=512), pool -> 256/graph -----
    k_prop<512,4,4><<<dim3(G_,4), 1024, 0, stream>>>(perm1, dinv1, csr1, A, Bb);
    k_gemm_mfma<2><<<512, b256, 0, stream>>>(Bb, convW[0], convB[0], A);
    k_pooltop<512,true><<<G_, 512, 0, stream>>>(A, poolP[0], poolBeta[0], cnt1,
            ei, ei + E_, srcA, dstA, cnt2, csr2, perm2, dinv2, Cc);

    // ----- stage 2: conv2 (L=2, nper=256), pool -> 128/graph -----
    k_prop<256,2,2><<<dim3(G_,4), 1024, 0, stream>>>(perm2, dinv2, csr2, Cc, Bb);
    k_gemm_mfma<1><<<512, b256, 0, stream>>>(Bb, convW[1], convB[1], A);
    k_pooltop<256,true><<<G_, 512, 0, stream>>>(A, poolP[1], poolBeta[1], cnt2,
            srcA, dstA, srcA, dstA, cnt3, csr3, perm3, dinv3, Cc);

    // ----- stage 3: conv3 (L=2, nper=128), pool -> 64/graph -----
    k_prop<128,2,1><<<dim3(G_,4), 1024, 0, stream>>>(perm3, dinv3, csr3, Cc, Bb);
    k_gemm_mfma<1><<<256, b256, 0, stream>>>(Bb, convW[2], convB[2], A);
    k_pooltop<128,false><<<G_, 512, 0, stream>>>(A, poolP[2], poolBeta[2], cnt3,
            nullptr, nullptr, nullptr, nullptr, nullptr, nullptr, nullptr, nullptr, Cc);

    // ----- readout -----
    k_meanmlp<<<G_, 128, 0, stream>>>(Cc, lin1W, lin1b, lin2W, lin2b, out);
}

// Round 5
// 309.075 us; speedup vs baseline: 1.1759x; 1.1053x over previous
//
#include <hip/hip_runtime.h>
#include <math.h>

#define G_     128
#define E_     524288
#define EPG    4096
#define DEGMAX 48

typedef __attribute__((ext_vector_type(8))) short bf16x8;
typedef __attribute__((ext_vector_type(4))) float f32x4;
typedef __attribute__((ext_vector_type(4))) unsigned short u16x4;

__device__ inline void split_bf16(float x, short& hi, short& lo){
    unsigned u = __float_as_uint(x);
    hi = (short)(u >> 16);
    float hf = __uint_as_float(u & 0xffff0000u);
    unsigned r = __float_as_uint(x - hf);
    lo = (short)(r >> 16);
}

// ---------------- stage-1 prep: CSR build + count + degree-sort + degree-prop + dinv ----------------
__global__ __launch_bounds__(512) void k_prep1(const int* __restrict__ ei,
        int* __restrict__ cnt, unsigned short* __restrict__ csrcp,
        int* __restrict__ permg, float* __restrict__ dinvg){
    __shared__ int   lcnt[512];
    __shared__ float y[1024];          // degree ping-pong
    __shared__ int   bins[64];
    __shared__ int   permS[512];
    int g = blockIdx.x, t = threadIdx.x, gbase = g*512;
    lcnt[t] = 0;
    if (t < 64) bins[t] = 0;
    __syncthreads();
    for (int i = t; i < EPG; i += 512){
        int e = g*EPG + i;
        int sv = ei[e] & 511;          // ids are g*512+local; 512-aligned -> &511 = local
        int d  = ei[E_ + e] & 511;
        int slot = atomicAdd(&lcnt[d], 1);
        if (slot < DEGMAX) csrcp[(size_t)(gbase + d)*DEGMAX + slot] = (unsigned short)sv;
    }
    __syncthreads();                   // csr (global, own block) + lcnt ready
    int rawc = lcnt[t];
    cnt[gbase + t] = rawc;             // GEMM score epilogue's node-strength term (unclamped)
    int dc = min(rawc, DEGMAX);
    atomicAdd(&bins[dc], 1);
    __syncthreads();
    if (t < 64){
        int v0 = bins[t], s = v0;
        #pragma unroll
        for (int off = 1; off < 64; off <<= 1){
            int n = __shfl_up(s, off);
            if (t >= off) s += n;
        }
        bins[t] = s - v0;              // exclusive prefix
    }
    __syncthreads();
    {
        int slot = atomicAdd(&bins[dc], 1);
        int pk = t | (dc << 16);
        permS[slot] = pk;
        permg[gbase + slot] = pk;
    }
    __syncthreads();
    int pk = permS[t];
    int pv = pk & 0xffff, pd = pk >> 16;
    y[pv] = 1.f;
    __syncthreads();
    float dacc = 1.f;
    int cur = 0;
    for (int l = 0; l < 4; l++){
        const float* la = &y[cur*512];
        float s = 0.f;
        int nq = (pd + 3) >> 2;
        const u16x4* cp = (const u16x4*)(csrcp + (size_t)(gbase + pv)*DEGMAX);
        u16x4 oc = cp[0];
        #pragma unroll 1
        for (int jq = 0; jq < nq; jq++){
            u16x4 ocn = cp[jq + 1];    // +8B over-read stays in workspace
            s += (la[(int)oc[0]] + la[(int)oc[1]]) + (la[(int)oc[2]] + la[(int)oc[3]]);
            oc = ocn;
        }
        if (nq) s -= (float)(nq*4 - pd) * la[0];
        y[(1^cur)*512 + pv] = s;
        dacc += s;
        __syncthreads();
        cur ^= 1;
    }
    dinvg[gbase + pv] = rsqrtf(fmaxf(dacc, 1e-12f));
}

// ---------------- per-graph feature prop ----------------
// OUT = dinv * (sum_l A^l)(dinv * x). R15 tiling (1024 thr, fq=4, 128B row stride =
// measured LDS b128 issue floor; 64B stride doubled conflicts in R16).
// SEL=true (stages 2/3): input row gathered via selg[] and scaled by thg[] -- this IS
// the pooling scatter, fused into the staging load (Cc buffer + scatter r/w deleted).
// SEL is a template param so stage-1's instantiation keeps its exact-64-VGPR budget.
// REGISTER HISTORY (DO NOT REPEAT): min-waves hints (R7/R14 launch_bounds(1024,8))
// force a 32-VGPR ceiling -> catastrophic scratch spill (FETCH 20->160MB).
template<int NPER, int L, int IT, bool SEL>
__global__ __launch_bounds__(1024)
void k_prop(const int* __restrict__ permg, const float* __restrict__ dinvg,
        const unsigned short* __restrict__ csrcp,
        const float* __restrict__ X, const int* __restrict__ selg,
        const float* __restrict__ thg, float* __restrict__ OUT){
    __shared__ __align__(16) float y[NPER*32];
    __shared__ float dinvs[NPER];
    int g = blockIdx.x, fq = blockIdx.y, gbase = g*NPER;
    int t = threadIdx.x;
    int f4 = (t & 7)*4;
    int fo = fq*32 + f4;
    if (t < NPER) dinvs[t] = dinvg[gbase + t];
    int pkr[IT];
    {
        int wv = t >> 6, gi = (t >> 3) & 7;
        #pragma unroll
        for (int it = 0; it < IT; it++){
            int ch = (it & 1) ? (15 - wv) : wv;
            pkr[it] = permg[gbase + (16*it + ch)*8 + gi];
        }
    }
    __syncthreads();
    float4 acc[IT];
    #pragma unroll
    for (int it = 0; it < IT; it++){
        int v = pkr[it] & 0xffff;
        float d = dinvs[v];
        size_t row;
        if (SEL){
            row = (size_t)selg[gbase + v];
            d *= thg[gbase + v];
        } else {
            row = (size_t)(gbase + v);
        }
        float4 w = *(const float4*)&X[row*128 + fo];
        w.x*=d; w.y*=d; w.z*=d; w.w*=d;
        acc[it] = w;
        *(float4*)&y[v*32 + f4] = w;
    }
    __syncthreads();
    for (int l = 0; l < L; l++){
        float4 s[IT];
        #pragma unroll
        for (int it = 0; it < IT; it++){
            int pk = pkr[it];
            int c = pk >> 16;
            int nq = (c + 3) >> 2;
            const u16x4* cp = (const u16x4*)(csrcp + (size_t)(gbase + (pk & 0xffff))*DEGMAX);
            float4 ss = make_float4(0.f,0.f,0.f,0.f);
            u16x4 oc = cp[0];
            #pragma unroll 1
            for (int jq = 0; jq < nq; jq++){
                u16x4 ocn = cp[jq + 1];
                float4 w0 = *(const float4*)&y[((int)oc[0])*32 + f4];
                float4 w1 = *(const float4*)&y[((int)oc[1])*32 + f4];
                float4 w2 = *(const float4*)&y[((int)oc[2])*32 + f4];
                float4 w3 = *(const float4*)&y[((int)oc[3])*32 + f4];
                ss.x += (w0.x + w1.x) + (w2.x + w3.x);
                ss.y += (w0.y + w1.y) + (w2.y + w3.y);
                ss.z += (w0.z + w1.z) + (w2.z + w3.z);
                ss.w += (w0.w + w1.w) + (w2.w + w3.w);
                oc = ocn;
            }
            if (nq){
                float fp = (float)(nq*4 - c);
                float4 z = *(const float4*)&y[f4];          // row 0 (broadcast)
                ss.x -= fp*z.x; ss.y -= fp*z.y; ss.z -= fp*z.z; ss.w -= fp*z.w;
            }
            s[it] = ss;
        }
        __syncthreads();
        #pragma unroll
        for (int it = 0; it < IT; it++){
            int v = pkr[it] & 0xffff;
            *(float4*)&y[v*32 + f4] = s[it];
            acc[it].x+=s[it].x; acc[it].y+=s[it].y; acc[it].z+=s[it].z; acc[it].w+=s[it].w;
        }
        __syncthreads();
    }
    #pragma unroll
    for (int it = 0; it < IT; it++){
        int v = pkr[it] & 0xffff;
        float d = dinvs[v];
        float4 w = acc[it];
        w.x*=d; w.y*=d; w.z*=d; w.w*=d;
        *(float4*)&OUT[(size_t)(gbase + v)*128 + fo] = w;
    }
}

// ---------------- split-bf16 MFMA GEMM + fused pooling score ----------------
// Y = X(Mx128) @ W(128x128) + bias. If score != nullptr also emits
// score[row] = (Y[row]) . (beta0*p/||p||) + beta1*cnt[row] using the acc registers
// (replaces pooltop's 33.5 MB re-read of Y with a 256 KB score array).
// Rows live in contiguous 16-lane groups -> 4x shfl_xor(1,2,4,8) reduces the dot.
template<int RT>
__global__ __launch_bounds__(256) void k_gemm_mfma(const float* __restrict__ X,
        const float* __restrict__ W, const float* __restrict__ bias, float* __restrict__ Y,
        const float* __restrict__ p, const float* __restrict__ beta,
        const int* __restrict__ cntv, float* __restrict__ score){
    __shared__ short wsh[128*136];
    __shared__ short wsl[128*136];
    __shared__ float bsh[128];
    __shared__ float qs[128];
    __shared__ float rednorm[64];
    int t = threadIdx.x;
    for (int e = t; e < 16384; e += 256){
        int k = e >> 7, n = e & 127;
        short hi, lo; split_bf16(W[e], hi, lo);
        wsh[n*136 + k] = hi; wsl[n*136 + k] = lo;
    }
    if (t < 128) bsh[t] = bias[t];
    if (score && t < 64){ float a = p[t], b = p[t+64]; rednorm[t] = a*a + b*b; }
    __syncthreads();
    float b1 = 0.f;
    if (score){
        if (t == 0){ float s = 0.f; for (int i = 0; i < 64; i++) s += rednorm[i]; rednorm[0] = sqrtf(s); }
        __syncthreads();
        if (t < 128) qs[t] = beta[0] * p[t] / rednorm[0];
        b1 = beta[1];
        __syncthreads();
    }
    int wave = t >> 6, lane = t & 63;
    int ln = lane & 15, q = lane >> 4;
    size_t rb0 = (size_t)blockIdx.x * (64*RT);
    for (int rt = 0; rt < RT; rt++){
        size_t rb = rb0 + (size_t)rt*64;
        const float* xrow = &X[(rb + wave*16 + ln)*128 + q*8];
        f32x4 acc[8];
        #pragma unroll
        for (int i = 0; i < 8; i++) acc[i] = (f32x4){0.f,0.f,0.f,0.f};
        #pragma unroll
        for (int kc = 0; kc < 4; kc++){
            float4 xa = *(const float4*)(xrow + kc*32);
            float4 xb = *(const float4*)(xrow + kc*32 + 4);
            bf16x8 ah, al; short hi, lo;
            split_bf16(xa.x, hi, lo); ah[0]=hi; al[0]=lo;
            split_bf16(xa.y, hi, lo); ah[1]=hi; al[1]=lo;
            split_bf16(xa.z, hi, lo); ah[2]=hi; al[2]=lo;
            split_bf16(xa.w, hi, lo); ah[3]=hi; al[3]=lo;
            split_bf16(xb.x, hi, lo); ah[4]=hi; al[4]=lo;
            split_bf16(xb.y, hi, lo); ah[5]=hi; al[5]=lo;
            split_bf16(xb.z, hi, lo); ah[6]=hi; al[6]=lo;
            split_bf16(xb.w, hi, lo); ah[7]=hi; al[7]=lo;
            #pragma unroll
            for (int nt = 0; nt < 8; nt++){
                int wo = (nt*16 + ln)*136 + kc*32 + q*8;
                bf16x8 bh = *(const bf16x8*)&wsh[wo];
                bf16x8 bl = *(const bf16x8*)&wsl[wo];
                acc[nt] = __builtin_amdgcn_mfma_f32_16x16x32_bf16(ah, bh, acc[nt], 0, 0, 0);
                acc[nt] = __builtin_amdgcn_mfma_f32_16x16x32_bf16(ah, bl, acc[nt], 0, 0, 0);
                acc[nt] = __builtin_amdgcn_mfma_f32_16x16x32_bf16(al, bh, acc[nt], 0, 0, 0);
            }
        }
        #pragma unroll
        for (int nt = 0; nt < 8; nt++){
            int c = nt*16 + ln;
            float bb = bsh[c];
            #pragma unroll
            for (int r = 0; r < 4; r++){
                Y[(rb + wave*16 + q*4 + r)*128 + c] = acc[nt][r] + bb;
            }
        }
        if (score){
            #pragma unroll
            for (int r = 0; r < 4; r++){
                float sp = 0.f;
                #pragma unroll
                for (int nt = 0; nt < 8; nt++){
                    int c = nt*16 + ln;
                    sp += (acc[nt][r] + bsh[c]) * qs[c];
                }
                sp += __shfl_xor(sp, 1);
                sp += __shfl_xor(sp, 2);
                sp += __shfl_xor(sp, 4);
                sp += __shfl_xor(sp, 8);
                if (ln == 0){
                    int row = (int)rb + wave*16 + q*4 + r;
                    score[row] = sp + b1 * (float)cntv[row];
                }
            }
        }
    }
}

// ---------------- pooling control: rank + sel/th emit + edge remap + next-stage prep ----------------
// Score precomputed by the GEMM epilogue; feature scatter fused into the next prop's
// staging load (sel/th). This kernel touches only control data (~12 MB stage 1).
template<int NPER, bool BUILD>
__global__ __launch_bounds__(512) void k_pooltop(const float* __restrict__ score_in,
        const int* __restrict__ esrc_in, const int* __restrict__ edst_in,
        int* __restrict__ esrc_out, int* __restrict__ edst_out,
        int* __restrict__ cnt_next, unsigned short* __restrict__ csrcp,
        int* __restrict__ permg, float* __restrict__ dinvg,
        int* __restrict__ selg, float* __restrict__ thg){
    __shared__ __align__(16) float sc[NPER];
    __shared__ int  nid[NPER];
    __shared__ int  lcnt[NPER/2];
    __shared__ int  bins[64];
    __shared__ int  permS[NPER/2];
    const int K = NPER/2;
    int g = blockIdx.x, t = threadIdx.x, gbase = g*NPER;
    if (BUILD && t < K) lcnt[t] = 0;
    if (t < 64) bins[t] = 0;
    if (t < NPER) sc[t] = score_in[gbase + t];
    __syncthreads();
    if (t < NPER){
        float s = sc[t];
        int rank = 0;
        const float4* sc4 = (const float4*)sc;
        #pragma unroll 8
        for (int j4 = 0; j4 < NPER/4; j4++){
            float4 v = sc4[j4];
            int j = j4*4;
            rank += (v.x > s) || (v.x == s && (j+0) < t);   // stable tie-break = lax.top_k
            rank += (v.y > s) || (v.y == s && (j+1) < t);
            rank += (v.z > s) || (v.z == s && (j+2) < t);
            rank += (v.w > s) || (v.w == s && (j+3) < t);
        }
        if (rank < K){
            nid[t] = g*K + rank;
            selg[g*K + rank] = gbase + t;       // source row in the conv-output buffer
            thg[g*K + rank]  = tanhf(s);
        } else nid[t] = -1;
    }
    __syncthreads();
    if (BUILD){
        for (int i = t; i < EPG; i += 512){
            int e = g*EPG + i;
            int d = edst_in[e];
            if (d < 0) continue;
            int s_ = esrc_in[e];
            int ns = nid[s_ - gbase], nd = nid[d - gbase];
            if ((ns | nd) < 0){ edst_out[e] = -1; }
            else {
                esrc_out[e] = ns; edst_out[e] = nd;
                int slot = atomicAdd(&lcnt[nd & (K-1)], 1);
                if (slot < DEGMAX) csrcp[(size_t)nd*DEGMAX + slot] = (unsigned short)(ns & (K-1));
            }
        }
        __syncthreads();               // csr (global, own block) + lcnt ready
        float* yd = sc;                // reuse: sc dead after rank; 2*K == NPER floats
        int rawc = 0, dc = 0;
        if (t < K){
            rawc = lcnt[t];
            cnt_next[g*K + t] = rawc;
            dc = min(rawc, DEGMAX);
            atomicAdd(&bins[dc], 1);
        }
        __syncthreads();
        if (t < 64){
            int v0 = bins[t], s = v0;
            #pragma unroll
            for (int off = 1; off < 64; off <<= 1){
                int n = __shfl_up(s, off);
                if (t >= off) s += n;
            }
            bins[t] = s - v0;
        }
        __syncthreads();
        if (t < K){
            int slot = atomicAdd(&bins[dc], 1);
            permS[slot] = t | (dc << 16);
            permg[g*K + slot] = permS[slot];
        }
        __syncthreads();
        int pv = 0, pd = 0;
        if (t < K){
            int pk = permS[t];
            pv = pk & 0xffff; pd = pk >> 16;
            yd[pv] = 1.f;
        }
        __syncthreads();
        float dacc = 1.f;
        int cur = 0;
        for (int l = 0; l < 2; l++){
            if (t < K){
                const float* la = &yd[cur*K];
                float s = 0.f;
                int nq = (pd + 3) >> 2;
                const u16x4* cp = (const u16x4*)(csrcp + (size_t)(g*K + pv)*DEGMAX);
                u16x4 oc = cp[0];
                #pragma unroll 1
                for (int jq = 0; jq < nq; jq++){
                    u16x4 ocn = cp[jq + 1];
                    s += (la[(int)oc[0]] + la[(int)oc[1]]) + (la[(int)oc[2]] + la[(int)oc[3]]);
                    oc = ocn;
                }
                if (nq) s -= (float)(nq*4 - pd) * la[0];
                yd[(1^cur)*K + pv] = s;
                dacc += s;
            }
            __syncthreads();
            cur ^= 1;
        }
        if (t < K) dinvg[g*K + pv] = rsqrtf(fmaxf(dacc, 1e-12f));
    }
}

// ---------------- fused readout: gather-mean (sel/th) + 2-layer MLP ----------------
__global__ __launch_bounds__(128) void k_meanmlp(const float* __restrict__ h,
        const int* __restrict__ selg, const float* __restrict__ thg,
        const float* __restrict__ W1, const float* __restrict__ b1,
        const float* __restrict__ W2, const float* __restrict__ b2,
        float* __restrict__ out){
    __shared__ float mr[128];
    int g = blockIdx.x, t = threadIdx.x;
    float s = 0.f;
    #pragma unroll 8
    for (int r = 0; r < 64; r++){
        int row = selg[g*64 + r];
        s += h[(size_t)row*128 + t] * thg[g*64 + r];
    }
    mr[t] = s * (1.f/64.f);
    __syncthreads();
    if (t < 64){
        float a = b1[t];
        #pragma unroll 8
        for (int k = 0; k < 128; k++) a += mr[k]*W1[k*64 + t];
        a = fmaxf(a, 0.f);
        float r = a * W2[t];
        #pragma unroll
        for (int off = 32; off > 0; off >>= 1) r += __shfl_down(r, off);
        if (t == 0) out[g] = r + b2[0];
    }
}

// ---------------- driver ----------------
extern "C" void kernel_launch(void* const* d_in, const int* in_sizes, int n_in,
                              void* d_out, int out_size, void* d_ws, size_t ws_size,
                              hipStream_t stream){
    (void)in_sizes; (void)n_in; (void)out_size; (void)ws_size;
    const float* x     = (const float*)d_in[0];
    const int*   ei    = (const int*)d_in[1];
    const float* lumpW = (const float*)d_in[3];
    const float* lumpb = (const float*)d_in[4];
    const float* convW[3]    = {(const float*)d_in[5], (const float*)d_in[7], (const float*)d_in[9]};
    const float* convB[3]    = {(const float*)d_in[6], (const float*)d_in[8], (const float*)d_in[10]};
    const float* poolP[3]    = {(const float*)d_in[11], (const float*)d_in[13], (const float*)d_in[15]};
    const float* poolBeta[3] = {(const float*)d_in[12], (const float*)d_in[14], (const float*)d_in[16]};
    const float* lin1W = (const float*)d_in[17];
    const float* lin1b = (const float*)d_in[18];
    const float* lin2W = (const float*)d_in[19];
    const float* lin2b = (const float*)d_in[20];
    float* out = (float*)d_out;

    char* w8 = (char*)d_ws;
    size_t off = 0;
    auto alloc = [&](size_t bytes)->char*{
        char* p = w8 + off; off += (bytes + 255) & ~(size_t)255; return p;
    };
    float* A     = (float*)alloc((size_t)65536*128*4);
    float* Bb    = (float*)alloc((size_t)65536*128*4);
    int*   srcA  = (int*)alloc((size_t)E_*4);
    int*   dstA  = (int*)alloc((size_t)E_*4);
    // csr1/csr2/csr3 contiguous: one memset zeroes pad slots
    unsigned short* csr1 = (unsigned short*)alloc((size_t)65536*DEGMAX*2);
    unsigned short* csr2 = (unsigned short*)alloc((size_t)32768*DEGMAX*2);
    unsigned short* csr3 = (unsigned short*)alloc((size_t)16384*DEGMAX*2);
    int*   cntA  = (int*)alloc((size_t)(65536+32768+16384)*4);
    int*   cnt1 = cntA, *cnt2 = cntA + 65536, *cnt3 = cntA + 98304;
    int*   perm1 = (int*)alloc((size_t)65536*4);
    int*   perm2 = (int*)alloc((size_t)32768*4);
    int*   perm3 = (int*)alloc((size_t)16384*4);
    float* dinv1 = (float*)alloc((size_t)65536*4);
    float* dinv2 = (float*)alloc((size_t)32768*4);
    float* dinv3 = (float*)alloc((size_t)16384*4);
    float* score1 = (float*)alloc((size_t)65536*4);
    float* score2 = (float*)alloc((size_t)32768*4);
    float* score3 = (float*)alloc((size_t)16384*4);
    int*   sel2  = (int*)alloc((size_t)32768*4);
    int*   sel3  = (int*)alloc((size_t)16384*4);
    int*   sel4  = (int*)alloc((size_t)8192*4);
    float* th2   = (float*)alloc((size_t)32768*4);
    float* th3   = (float*)alloc((size_t)16384*4);
    float* th4   = (float*)alloc((size_t)8192*4);

    dim3 b256(256);

    size_t zbytes = (size_t)(65536+32768+16384)*DEGMAX*2;
    hipMemsetAsync(csr1, 0, zbytes, stream);
    k_gemm_mfma<2><<<512, b256, 0, stream>>>(x, lumpW, lumpb, A,
            nullptr, nullptr, nullptr, nullptr);
    k_prep1<<<G_, 512, 0, stream>>>(ei, cnt1, csr1, perm1, dinv1);

    // ----- stage 1: conv1 (L=4, nper=512), pool -> 256/graph -----
    k_prop<512,4,4,false><<<dim3(G_,4), 1024, 0, stream>>>(perm1, dinv1, csr1, A,
            nullptr, nullptr, Bb);
    k_gemm_mfma<2><<<512, b256, 0, stream>>>(Bb, convW[0], convB[0], A,
            poolP[0], poolBeta[0], cnt1, score1);
    k_pooltop<512,true><<<G_, 512, 0, stream>>>(score1, ei, ei + E_, srcA, dstA,
            cnt2, csr2, perm2, dinv2, sel2, th2);

    // ----- stage 2: conv2 (L=2, nper=256), pool -> 128/graph -----
    k_prop<256,2,2,true><<<dim3(G_,4), 1024, 0, stream>>>(perm2, dinv2, csr2, A,
            sel2, th2, Bb);
    k_gemm_mfma<1><<<512, b256, 0, stream>>>(Bb, convW[1], convB[1], A,
            poolP[1], poolBeta[1], cnt2, score2);
    k_pooltop<256,true><<<G_, 512, 0, stream>>>(score2, srcA, dstA, srcA, dstA,
            cnt3, csr3, perm3, dinv3, sel3, th3);

    // ----- stage 3: conv3 (L=2, nper=128), pool -> 64/graph -----
    k_prop<128,2,1,true><<<dim3(G_,4), 1024, 0, stream>>>(perm3, dinv3, csr3, A,
            sel3, th3, Bb);
    k_gemm_mfma<1><<<256, b256, 0, stream>>>(Bb, convW[2], convB[2], A,
            poolP[2], poolBeta[2], cnt3, score3);
    k_pooltop<128,false><<<G_, 512, 0, stream>>>(score3, nullptr, nullptr, nullptr, nullptr,
            nullptr, nullptr, nullptr, nullptr, sel4, th4);

    // ----- readout -----
    k_meanmlp<<<G_, 128, 0, stream>>>(A, sel4, th4, lin1W, lin1b, lin2W, lin2b, out);
}

// Round 6
// 300.038 us; speedup vs baseline: 1.2113x; 1.0301x over previous
//
#include <hip/hip_runtime.h>
#include <math.h>

#define G_     128
#define E_     524288
#define EPG    4096
#define DEGMAX 48

typedef __attribute__((ext_vector_type(8))) short bf16x8;
typedef __attribute__((ext_vector_type(4))) float f32x4;
typedef __attribute__((ext_vector_type(4))) unsigned short u16x4;

__device__ inline void split_bf16(float x, short& hi, short& lo){
    unsigned u = __float_as_uint(x);
    hi = (short)(u >> 16);
    float hf = __uint_as_float(u & 0xffff0000u);
    unsigned r = __float_as_uint(x - hf);
    lo = (short)(r >> 16);
}

// ================= shared GEMM body: Y = X(Mx128) @ W(128x128) + bias (+score) =================
// split-bf16 (3 MFMA) for f32 accuracy. W hi/lo staged in LDS (byte offsets into smem).
// If score != nullptr: score[row] = Y[row].(beta0*p/||p||) + beta1*cnt[row] from acc regs.
// smem layout: wsh[0,34816) wsl[34816,69632) bsh[69632,70144) qs[70144,70656) red[70656,70912)
template<int WAVES>
__device__ void gemm_body(char* smem, int bid, const float* __restrict__ X,
        const float* __restrict__ W, const float* __restrict__ bias, float* __restrict__ Y,
        const float* __restrict__ p, const float* __restrict__ beta,
        const int* __restrict__ cntv, float* __restrict__ score){
    short* wsh = (short*)smem;
    short* wsl = (short*)(smem + 34816);
    float* bsh = (float*)(smem + 69632);
    float* qs  = (float*)(smem + 70144);
    float* rednorm = (float*)(smem + 70656);
    const int NT = WAVES*64;
    int t = threadIdx.x;
    for (int e = t; e < 16384; e += NT){
        int k = e >> 7, n = e & 127;
        short hi, lo; split_bf16(W[e], hi, lo);
        wsh[n*136 + k] = hi; wsl[n*136 + k] = lo;
    }
    if (t < 128) bsh[t] = bias[t];
    if (score && t < 64){ float a = p[t], b = p[t+64]; rednorm[t] = a*a + b*b; }
    __syncthreads();
    float b1 = 0.f;
    if (score){
        if (t == 0){ float s = 0.f; for (int i = 0; i < 64; i++) s += rednorm[i]; rednorm[0] = sqrtf(s); }
        __syncthreads();
        if (t < 128) qs[t] = beta[0] * p[t] / rednorm[0];
        b1 = beta[1];
        __syncthreads();
    }
    int wave = t >> 6, lane = t & 63;
    int ln = lane & 15, q = lane >> 4;
    size_t rb = (size_t)bid * (WAVES*16);
    const float* xrow = &X[(rb + wave*16 + ln)*128 + q*8];
    f32x4 acc[8];
    #pragma unroll
    for (int i = 0; i < 8; i++) acc[i] = (f32x4){0.f,0.f,0.f,0.f};
    #pragma unroll
    for (int kc = 0; kc < 4; kc++){
        float4 xa = *(const float4*)(xrow + kc*32);
        float4 xb = *(const float4*)(xrow + kc*32 + 4);
        bf16x8 ah, al; short hi, lo;
        split_bf16(xa.x, hi, lo); ah[0]=hi; al[0]=lo;
        split_bf16(xa.y, hi, lo); ah[1]=hi; al[1]=lo;
        split_bf16(xa.z, hi, lo); ah[2]=hi; al[2]=lo;
        split_bf16(xa.w, hi, lo); ah[3]=hi; al[3]=lo;
        split_bf16(xb.x, hi, lo); ah[4]=hi; al[4]=lo;
        split_bf16(xb.y, hi, lo); ah[5]=hi; al[5]=lo;
        split_bf16(xb.z, hi, lo); ah[6]=hi; al[6]=lo;
        split_bf16(xb.w, hi, lo); ah[7]=hi; al[7]=lo;
        #pragma unroll
        for (int nt = 0; nt < 8; nt++){
            int wo = (nt*16 + ln)*136 + kc*32 + q*8;
            bf16x8 bh = *(const bf16x8*)&wsh[wo];
            bf16x8 bl = *(const bf16x8*)&wsl[wo];
            acc[nt] = __builtin_amdgcn_mfma_f32_16x16x32_bf16(ah, bh, acc[nt], 0, 0, 0);
            acc[nt] = __builtin_amdgcn_mfma_f32_16x16x32_bf16(ah, bl, acc[nt], 0, 0, 0);
            acc[nt] = __builtin_amdgcn_mfma_f32_16x16x32_bf16(al, bh, acc[nt], 0, 0, 0);
        }
    }
    #pragma unroll
    for (int nt = 0; nt < 8; nt++){
        int c = nt*16 + ln;
        float bb = bsh[c];
        #pragma unroll
        for (int r = 0; r < 4; r++){
            Y[(rb + wave*16 + q*4 + r)*128 + c] = acc[nt][r] + bb;
        }
    }
    if (score){
        #pragma unroll
        for (int r = 0; r < 4; r++){
            float sp = 0.f;
            #pragma unroll
            for (int nt = 0; nt < 8; nt++){
                int c = nt*16 + ln;
                sp += (acc[nt][r] + bsh[c]) * qs[c];
            }
            sp += __shfl_xor(sp, 1);
            sp += __shfl_xor(sp, 2);
            sp += __shfl_xor(sp, 4);
            sp += __shfl_xor(sp, 8);
            if (ln == 0){
                int row = (int)rb + wave*16 + q*4 + r;
                score[row] = sp + b1 * (float)cntv[row];
            }
        }
    }
}

// ================= stage-1 prep body: CSR build + count + sort + degree-prop + dinv =================
// Pads [dc, ceil4(dc)) zeroed explicitly -> the 23 MB per-iteration CSR memset is deleted.
// smem layout: lcnt[0,2048) y[2048,6144) bins[6144,6400) permS[6400,8448)
__device__ void prep1_body(char* smem, int g, const int* __restrict__ ei,
        int* __restrict__ cnt, unsigned short* __restrict__ csrcp,
        int* __restrict__ permg, float* __restrict__ dinvg){
    int*   lcnt  = (int*)smem;
    float* y     = (float*)(smem + 2048);
    int*   bins  = (int*)(smem + 6144);
    int*   permS = (int*)(smem + 6400);
    int t = threadIdx.x, gbase = g*512;
    lcnt[t] = 0;
    if (t < 64) bins[t] = 0;
    __syncthreads();
    for (int i = t; i < EPG; i += 512){
        int e = g*EPG + i;
        int sv = ei[e] & 511;          // ids are g*512+local; 512-aligned -> &511 = local
        int d  = ei[E_ + e] & 511;
        int slot = atomicAdd(&lcnt[d], 1);
        if (slot < DEGMAX) csrcp[(size_t)(gbase + d)*DEGMAX + slot] = (unsigned short)sv;
    }
    __syncthreads();                   // csr (global, own block) + lcnt ready
    int rawc = lcnt[t];
    cnt[gbase + t] = rawc;             // GEMM score epilogue's node-strength term (unclamped)
    int dc = min(rawc, DEGMAX);
    {   // zero only the pad slots the quad loop reads: [dc, ceil4(dc))
        int e4 = (dc + 3) & ~3;
        for (int s2 = dc; s2 < e4; s2++) csrcp[(size_t)(gbase + t)*DEGMAX + s2] = 0;
    }
    atomicAdd(&bins[dc], 1);
    __syncthreads();
    if (t < 64){
        int v0 = bins[t], s = v0;
        #pragma unroll
        for (int off = 1; off < 64; off <<= 1){
            int n = __shfl_up(s, off);
            if (t >= off) s += n;
        }
        bins[t] = s - v0;              // exclusive prefix
    }
    __syncthreads();
    {
        int slot = atomicAdd(&bins[dc], 1);
        int pk = t | (dc << 16);
        permS[slot] = pk;
        permg[gbase + slot] = pk;
    }
    __syncthreads();
    int pk = permS[t];
    int pv = pk & 0xffff, pd = pk >> 16;
    y[pv] = 1.f;
    __syncthreads();
    float dacc = 1.f;
    int cur = 0;
    for (int l = 0; l < 4; l++){
        const float* la = &y[cur*512];
        float s = 0.f;
        int nq = (pd + 3) >> 2;
        const u16x4* cp = (const u16x4*)(csrcp + (size_t)(gbase + pv)*DEGMAX);
        u16x4 oc = cp[0];
        #pragma unroll 1
        for (int jq = 0; jq < nq; jq++){
            u16x4 ocn = cp[jq + 1];    // +8B over-read stays in workspace
            s += (la[(int)oc[0]] + la[(int)oc[1]]) + (la[(int)oc[2]] + la[(int)oc[3]]);
            oc = ocn;
        }
        if (nq) s -= (float)(nq*4 - pd) * la[0];
        y[(1^cur)*512 + pv] = s;
        dacc += s;
        __syncthreads();
        cur ^= 1;
    }
    dinvg[gbase + pv] = rsqrtf(fmaxf(dacc, 1e-12f));
}

// ================= merged launch: prep1 (blocks 0..127) || lump GEMM (blocks 128..639) =================
// prep blocks dispatch FIRST so they overlap the gemm instead of trailing it.
__global__ __launch_bounds__(512) void k_lump_prep(const float* __restrict__ x,
        const float* __restrict__ lumpW, const float* __restrict__ lumpb, float* __restrict__ A,
        const int* __restrict__ ei, int* __restrict__ cnt, unsigned short* __restrict__ csr1,
        int* __restrict__ perm1, float* __restrict__ dinv1){
    __shared__ __align__(16) char smem[70912];
    if (blockIdx.x < G_) prep1_body(smem, blockIdx.x, ei, cnt, csr1, perm1, dinv1);
    else gemm_body<8>(smem, blockIdx.x - G_, x, lumpW, lumpb, A,
                      nullptr, nullptr, nullptr, nullptr);
}

// ================= standalone GEMM (+score) =================
template<int WAVES>
__global__ __launch_bounds__(WAVES*64) void k_gemm_mfma(const float* __restrict__ X,
        const float* __restrict__ W, const float* __restrict__ bias, float* __restrict__ Y,
        const float* __restrict__ p, const float* __restrict__ beta,
        const int* __restrict__ cntv, float* __restrict__ score){
    __shared__ __align__(16) char smem[70912];
    gemm_body<WAVES>(smem, blockIdx.x, X, W, bias, Y, p, beta, cntv, score);
}

// ---------------- per-graph feature prop ----------------
// OUT = dinv * (sum_l A^l)(dinv * x). R15 tiling (1024 thr, fq=4, 128B row stride =
// measured LDS b128 issue floor; 64B stride doubled conflicts in R16).
// SEL=true (stages 2/3): input row gathered via selg[]/thg[] = the pooling scatter
// fused into the staging load. UNCHANGED since R18 (protect 64-VGPR/2-block point).
// REGISTER HISTORY (DO NOT REPEAT): min-waves hints (R7/R14 launch_bounds(1024,8))
// force a 32-VGPR ceiling -> catastrophic scratch spill (FETCH 20->160MB).
template<int NPER, int L, int IT, bool SEL>
__global__ __launch_bounds__(1024)
void k_prop(const int* __restrict__ permg, const float* __restrict__ dinvg,
        const unsigned short* __restrict__ csrcp,
        const float* __restrict__ X, const int* __restrict__ selg,
        const float* __restrict__ thg, float* __restrict__ OUT){
    __shared__ __align__(16) float y[NPER*32];
    __shared__ float dinvs[NPER];
    int g = blockIdx.x, fq = blockIdx.y, gbase = g*NPER;
    int t = threadIdx.x;
    int f4 = (t & 7)*4;
    int fo = fq*32 + f4;
    if (t < NPER) dinvs[t] = dinvg[gbase + t];
    int pkr[IT];
    {
        int wv = t >> 6, gi = (t >> 3) & 7;
        #pragma unroll
        for (int it = 0; it < IT; it++){
            int ch = (it & 1) ? (15 - wv) : wv;
            pkr[it] = permg[gbase + (16*it + ch)*8 + gi];
        }
    }
    __syncthreads();
    float4 acc[IT];
    #pragma unroll
    for (int it = 0; it < IT; it++){
        int v = pkr[it] & 0xffff;
        float d = dinvs[v];
        size_t row;
        if (SEL){
            row = (size_t)selg[gbase + v];
            d *= thg[gbase + v];
        } else {
            row = (size_t)(gbase + v);
        }
        float4 w = *(const float4*)&X[row*128 + fo];
        w.x*=d; w.y*=d; w.z*=d; w.w*=d;
        acc[it] = w;
        *(float4*)&y[v*32 + f4] = w;
    }
    __syncthreads();
    for (int l = 0; l < L; l++){
        float4 s[IT];
        #pragma unroll
        for (int it = 0; it < IT; it++){
            int pk = pkr[it];
            int c = pk >> 16;
            int nq = (c + 3) >> 2;
            const u16x4* cp = (const u16x4*)(csrcp + (size_t)(gbase + (pk & 0xffff))*DEGMAX);
            float4 ss = make_float4(0.f,0.f,0.f,0.f);
            u16x4 oc = cp[0];
            #pragma unroll 1
            for (int jq = 0; jq < nq; jq++){
                u16x4 ocn = cp[jq + 1];
                float4 w0 = *(const float4*)&y[((int)oc[0])*32 + f4];
                float4 w1 = *(const float4*)&y[((int)oc[1])*32 + f4];
                float4 w2 = *(const float4*)&y[((int)oc[2])*32 + f4];
                float4 w3 = *(const float4*)&y[((int)oc[3])*32 + f4];
                ss.x += (w0.x + w1.x) + (w2.x + w3.x);
                ss.y += (w0.y + w1.y) + (w2.y + w3.y);
                ss.z += (w0.z + w1.z) + (w2.z + w3.z);
                ss.w += (w0.w + w1.w) + (w2.w + w3.w);
                oc = ocn;
            }
            if (nq){
                float fp = (float)(nq*4 - c);
                float4 z = *(const float4*)&y[f4];          // row 0 (broadcast)
                ss.x -= fp*z.x; ss.y -= fp*z.y; ss.z -= fp*z.z; ss.w -= fp*z.w;
            }
            s[it] = ss;
        }
        __syncthreads();
        #pragma unroll
        for (int it = 0; it < IT; it++){
            int v = pkr[it] & 0xffff;
            *(float4*)&y[v*32 + f4] = s[it];
            acc[it].x+=s[it].x; acc[it].y+=s[it].y; acc[it].z+=s[it].z; acc[it].w+=s[it].w;
        }
        __syncthreads();
    }
    #pragma unroll
    for (int it = 0; it < IT; it++){
        int v = pkr[it] & 0xffff;
        float d = dinvs[v];
        float4 w = acc[it];
        w.x*=d; w.y*=d; w.z*=d; w.w*=d;
        *(float4*)&OUT[(size_t)(gbase + v)*128 + fo] = w;
    }
}

// ---------------- pooling control: rank + sel/th emit + edge remap + next-stage prep ----------------
// Score precomputed by GEMM epilogue; feature scatter fused into next prop's load.
// BUILD tail zeroes next-stage CSR pad slots (memset deleted).
template<int NPER, bool BUILD>
__global__ __launch_bounds__(512) void k_pooltop(const float* __restrict__ score_in,
        const int* __restrict__ esrc_in, const int* __restrict__ edst_in,
        int* __restrict__ esrc_out, int* __restrict__ edst_out,
        int* __restrict__ cnt_next, unsigned short* __restrict__ csrcp,
        int* __restrict__ permg, float* __restrict__ dinvg,
        int* __restrict__ selg, float* __restrict__ thg){
    __shared__ __align__(16) float sc[NPER];
    __shared__ int  nid[NPER];
    __shared__ int  lcnt[NPER/2];
    __shared__ int  bins[64];
    __shared__ int  permS[NPER/2];
    const int K = NPER/2;
    int g = blockIdx.x, t = threadIdx.x, gbase = g*NPER;
    if (t < K) lcnt[t] = 0;
    if (t < 64) bins[t] = 0;
    if (t < NPER) sc[t] = score_in[gbase + t];
    __syncthreads();
    if (t < NPER){
        float s = sc[t];
        int rank = 0;
        const float4* sc4 = (const float4*)sc;
        #pragma unroll 8
        for (int j4 = 0; j4 < NPER/4; j4++){
            float4 v = sc4[j4];
            int j = j4*4;
            rank += (v.x > s) || (v.x == s && (j+0) < t);   // stable tie-break = lax.top_k
            rank += (v.y > s) || (v.y == s && (j+1) < t);
            rank += (v.z > s) || (v.z == s && (j+2) < t);
            rank += (v.w > s) || (v.w == s && (j+3) < t);
        }
        if (rank < K){
            nid[t] = g*K + rank;
            selg[g*K + rank] = gbase + t;       // source row in the conv-output buffer
            thg[g*K + rank]  = tanhf(s);
        } else nid[t] = -1;
    }
    __syncthreads();
    if (BUILD){
        for (int i = t; i < EPG; i += 512){
            int e = g*EPG + i;
            int d = edst_in[e];
            if (d < 0) continue;
            int s_ = esrc_in[e];
            int ns = nid[s_ - gbase], nd = nid[d - gbase];
            if ((ns | nd) < 0){ edst_out[e] = -1; }
            else {
                esrc_out[e] = ns; edst_out[e] = nd;
                int slot = atomicAdd(&lcnt[nd & (K-1)], 1);
                if (slot < DEGMAX) csrcp[(size_t)nd*DEGMAX + slot] = (unsigned short)(ns & (K-1));
            }
        }
        __syncthreads();               // csr (global, own block) + lcnt ready
        float* yd = sc;                // reuse: sc dead after rank; 2*K == NPER floats
        int rawc = 0, dc = 0;
        if (t < K){
            rawc = lcnt[t];
            cnt_next[g*K + t] = rawc;
            dc = min(rawc, DEGMAX);
            int e4 = (dc + 3) & ~3;    // zero pad slots the quad loop reads
            for (int s2 = dc; s2 < e4; s2++) csrcp[(size_t)(g*K + t)*DEGMAX + s2] = 0;
            atomicAdd(&bins[dc], 1);
        }
        __syncthreads();
        if (t < 64){
            int v0 = bins[t], s = v0;
            #pragma unroll
            for (int off = 1; off < 64; off <<= 1){
                int n = __shfl_up(s, off);
                if (t >= off) s += n;
            }
            bins[t] = s - v0;
        }
        __syncthreads();
        if (t < K){
            int slot = atomicAdd(&bins[dc], 1);
            permS[slot] = t | (dc << 16);
            permg[g*K + slot] = permS[slot];
        }
        __syncthreads();
        int pv = 0, pd = 0;
        if (t < K){
            int pk = permS[t];
            pv = pk & 0xffff; pd = pk >> 16;
            yd[pv] = 1.f;
        }
        __syncthreads();
        float dacc = 1.f;
        int cur = 0;
        for (int l = 0; l < 2; l++){
            if (t < K){
                const float* la = &yd[cur*K];
                float s = 0.f;
                int nq = (pd + 3) >> 2;
                const u16x4* cp = (const u16x4*)(csrcp + (size_t)(g*K + pv)*DEGMAX);
                u16x4 oc = cp[0];
                #pragma unroll 1
                for (int jq = 0; jq < nq; jq++){
                    u16x4 ocn = cp[jq + 1];
                    s += (la[(int)oc[0]] + la[(int)oc[1]]) + (la[(int)oc[2]] + la[(int)oc[3]]);
                    oc = ocn;
                }
                if (nq) s -= (float)(nq*4 - pd) * la[0];
                yd[(1^cur)*K + pv] = s;
                dacc += s;
            }
            __syncthreads();
            cur ^= 1;
        }
        if (t < K) dinvg[g*K + pv] = rsqrtf(fmaxf(dacc, 1e-12f));
    }
}

// ---------------- merged final stage: rank(128->64) + gather-mean + 2-layer MLP ----------------
__global__ __launch_bounds__(128) void k_pool3_mean(const float* __restrict__ score_in,
        const float* __restrict__ h, const float* __restrict__ W1, const float* __restrict__ b1,
        const float* __restrict__ W2, const float* __restrict__ b2, float* __restrict__ out){
    __shared__ __align__(16) float sc[128];
    __shared__ int   selS[64];
    __shared__ float thS[64];
    __shared__ float mr[128];
    int g = blockIdx.x, t = threadIdx.x;
    sc[t] = score_in[g*128 + t];
    __syncthreads();
    {
        float s = sc[t];
        int rank = 0;
        const float4* sc4 = (const float4*)sc;
        #pragma unroll 8
        for (int j4 = 0; j4 < 32; j4++){
            float4 v = sc4[j4];
            int j = j4*4;
            rank += (v.x > s) || (v.x == s && (j+0) < t);   // stable tie-break = lax.top_k
            rank += (v.y > s) || (v.y == s && (j+1) < t);
            rank += (v.z > s) || (v.z == s && (j+2) < t);
            rank += (v.w > s) || (v.w == s && (j+3) < t);
        }
        if (rank < 64){ selS[rank] = g*128 + t; thS[rank] = tanhf(s); }
    }
    __syncthreads();
    float s = 0.f;
    #pragma unroll 8
    for (int r = 0; r < 64; r++) s += h[(size_t)selS[r]*128 + t] * thS[r];
    mr[t] = s * (1.f/64.f);
    __syncthreads();
    if (t < 64){
        float a = b1[t];
        #pragma unroll 8
        for (int k = 0; k < 128; k++) a += mr[k]*W1[k*64 + t];
        a = fmaxf(a, 0.f);
        float r = a * W2[t];
        #pragma unroll
        for (int off = 32; off > 0; off >>= 1) r += __shfl_down(r, off);
        if (t == 0) out[g] = r + b2[0];
    }
}

// ---------------- driver: 10 launches (was 13; memset / build / meanmlp nodes folded) ----------------
extern "C" void kernel_launch(void* const* d_in, const int* in_sizes, int n_in,
                              void* d_out, int out_size, void* d_ws, size_t ws_size,
                              hipStream_t stream){
    (void)in_sizes; (void)n_in; (void)out_size; (void)ws_size;
    const float* x     = (const float*)d_in[0];
    const int*   ei    = (const int*)d_in[1];
    const float* lumpW = (const float*)d_in[3];
    const float* lumpb = (const float*)d_in[4];
    const float* convW[3]    = {(const float*)d_in[5], (const float*)d_in[7], (const float*)d_in[9]};
    const float* convB[3]    = {(const float*)d_in[6], (const float*)d_in[8], (const float*)d_in[10]};
    const float* poolP[3]    = {(const float*)d_in[11], (const float*)d_in[13], (const float*)d_in[15]};
    const float* poolBeta[3] = {(const float*)d_in[12], (const float*)d_in[14], (const float*)d_in[16]};
    const float* lin1W = (const float*)d_in[17];
    const float* lin1b = (const float*)d_in[18];
    const float* lin2W = (const float*)d_in[19];
    const float* lin2b = (const float*)d_in[20];
    float* out = (float*)d_out;

    char* w8 = (char*)d_ws;
    size_t off = 0;
    auto alloc = [&](size_t bytes)->char*{
        char* p = w8 + off; off += (bytes + 255) & ~(size_t)255; return p;
    };
    float* A     = (float*)alloc((size_t)65536*128*4);
    float* Bb    = (float*)alloc((size_t)65536*128*4);
    int*   srcA  = (int*)alloc((size_t)E_*4);
    int*   dstA  = (int*)alloc((size_t)E_*4);
    unsigned short* csr1 = (unsigned short*)alloc((size_t)65536*DEGMAX*2);
    unsigned short* csr2 = (unsigned short*)alloc((size_t)32768*DEGMAX*2);
    unsigned short* csr3 = (unsigned short*)alloc((size_t)16384*DEGMAX*2);
    int*   cntA  = (int*)alloc((size_t)(65536+32768+16384)*4);
    int*   cnt1 = cntA, *cnt2 = cntA + 65536, *cnt3 = cntA + 98304;
    int*   perm1 = (int*)alloc((size_t)65536*4);
    int*   perm2 = (int*)alloc((size_t)32768*4);
    int*   perm3 = (int*)alloc((size_t)16384*4);
    float* dinv1 = (float*)alloc((size_t)65536*4);
    float* dinv2 = (float*)alloc((size_t)32768*4);
    float* dinv3 = (float*)alloc((size_t)16384*4);
    float* score1 = (float*)alloc((size_t)65536*4);
    float* score2 = (float*)alloc((size_t)32768*4);
    float* score3 = (float*)alloc((size_t)16384*4);
    int*   sel2  = (int*)alloc((size_t)32768*4);
    int*   sel3  = (int*)alloc((size_t)16384*4);
    float* th2   = (float*)alloc((size_t)32768*4);
    float* th3   = (float*)alloc((size_t)16384*4);

    // ----- prep1 (blocks 0..127) || lump GEMM (blocks 128..639), no memset -----
    k_lump_prep<<<G_ + 512, 512, 0, stream>>>(x, lumpW, lumpb, A, ei, cnt1, csr1, perm1, dinv1);

    // ----- stage 1: conv1 (L=4, nper=512), pool -> 256/graph -----
    k_prop<512,4,4,false><<<dim3(G_,4), 1024, 0, stream>>>(perm1, dinv1, csr1, A,
            nullptr, nullptr, Bb);
    k_gemm_mfma<8><<<512, 512, 0, stream>>>(Bb, convW[0], convB[0], A,
            poolP[0], poolBeta[0], cnt1, score1);
    k_pooltop<512,true><<<G_, 512, 0, stream>>>(score1, ei, ei + E_, srcA, dstA,
            cnt2, csr2, perm2, dinv2, sel2, th2);

    // ----- stage 2: conv2 (L=2, nper=256), pool -> 128/graph -----
    k_prop<256,2,2,true><<<dim3(G_,4), 1024, 0, stream>>>(perm2, dinv2, csr2, A,
            sel2, th2, Bb);
    k_gemm_mfma<8><<<256, 512, 0, stream>>>(Bb, convW[1], convB[1], A,
            poolP[1], poolBeta[1], cnt2, score2);
    k_pooltop<256,true><<<G_, 512, 0, stream>>>(score2, srcA, dstA, srcA, dstA,
            cnt3, csr3, perm3, dinv3, sel3, th3);

    // ----- stage 3: conv3 (L=2, nper=128), pool -> 64/graph -----
    k_prop<128,2,1,true><<<dim3(G_,4), 1024, 0, stream>>>(perm3, dinv3, csr3, A,
            sel3, th3, Bb);
    k_gemm_mfma<4><<<256, 256, 0, stream>>>(Bb, convW[2], convB[2], A,
            poolP[2], poolBeta[2], cnt3, score3);

    // ----- final: rank + gather-mean + MLP -----
    k_pool3_mean<<<G_, 128, 0, stream>>>(score3, A, lin1W, lin1b, lin2W, lin2b, out);
}

// Round 7
// 297.974 us; speedup vs baseline: 1.2197x; 1.0069x over previous
//
#include <hip/hip_runtime.h>
#include <math.h>

#define G_     128
#define E_     524288
#define EPG    4096
#define DEGMAX 48

typedef __attribute__((ext_vector_type(8))) short bf16x8;
typedef __attribute__((ext_vector_type(4))) float f32x4;
typedef __attribute__((ext_vector_type(4))) unsigned short u16x4;

__device__ inline void split_bf16(float x, short& hi, short& lo){
    unsigned u = __float_as_uint(x);
    hi = (short)(u >> 16);
    float hf = __uint_as_float(u & 0xffff0000u);
    unsigned r = __float_as_uint(x - hf);
    lo = (short)(r >> 16);
}

// ================= shared GEMM body: Y = X(Mx128) @ W(128x128) + bias (+score) =================
// smem layout: wsh[0,34816) wsl[34816,69632) bsh[69632,70144) qs[70144,70656) red[70656,70912)
template<int WAVES>
__device__ void gemm_body(char* smem, int bid, const float* __restrict__ X,
        const float* __restrict__ W, const float* __restrict__ bias, float* __restrict__ Y,
        const float* __restrict__ p, const float* __restrict__ beta,
        const int* __restrict__ cntv, float* __restrict__ score){
    short* wsh = (short*)smem;
    short* wsl = (short*)(smem + 34816);
    float* bsh = (float*)(smem + 69632);
    float* qs  = (float*)(smem + 70144);
    float* rednorm = (float*)(smem + 70656);
    const int NT = WAVES*64;
    int t = threadIdx.x;
    for (int e = t; e < 16384; e += NT){
        int k = e >> 7, n = e & 127;
        short hi, lo; split_bf16(W[e], hi, lo);
        wsh[n*136 + k] = hi; wsl[n*136 + k] = lo;
    }
    if (t < 128) bsh[t] = bias[t];
    if (score && t < 64){ float a = p[t], b = p[t+64]; rednorm[t] = a*a + b*b; }
    __syncthreads();
    float b1 = 0.f;
    if (score){
        if (t == 0){ float s = 0.f; for (int i = 0; i < 64; i++) s += rednorm[i]; rednorm[0] = sqrtf(s); }
        __syncthreads();
        if (t < 128) qs[t] = beta[0] * p[t] / rednorm[0];
        b1 = beta[1];
        __syncthreads();
    }
    int wave = t >> 6, lane = t & 63;
    int ln = lane & 15, q = lane >> 4;
    size_t rb = (size_t)bid * (WAVES*16);
    const float* xrow = &X[(rb + wave*16 + ln)*128 + q*8];
    f32x4 acc[8];
    #pragma unroll
    for (int i = 0; i < 8; i++) acc[i] = (f32x4){0.f,0.f,0.f,0.f};
    #pragma unroll
    for (int kc = 0; kc < 4; kc++){
        float4 xa = *(const float4*)(xrow + kc*32);
        float4 xb = *(const float4*)(xrow + kc*32 + 4);
        bf16x8 ah, al; short hi, lo;
        split_bf16(xa.x, hi, lo); ah[0]=hi; al[0]=lo;
        split_bf16(xa.y, hi, lo); ah[1]=hi; al[1]=lo;
        split_bf16(xa.z, hi, lo); ah[2]=hi; al[2]=lo;
        split_bf16(xa.w, hi, lo); ah[3]=hi; al[3]=lo;
        split_bf16(xb.x, hi, lo); ah[4]=hi; al[4]=lo;
        split_bf16(xb.y, hi, lo); ah[5]=hi; al[5]=lo;
        split_bf16(xb.z, hi, lo); ah[6]=hi; al[6]=lo;
        split_bf16(xb.w, hi, lo); ah[7]=hi; al[7]=lo;
        #pragma unroll
        for (int nt = 0; nt < 8; nt++){
            int wo = (nt*16 + ln)*136 + kc*32 + q*8;
            bf16x8 bh = *(const bf16x8*)&wsh[wo];
            bf16x8 bl = *(const bf16x8*)&wsl[wo];
            acc[nt] = __builtin_amdgcn_mfma_f32_16x16x32_bf16(ah, bh, acc[nt], 0, 0, 0);
            acc[nt] = __builtin_amdgcn_mfma_f32_16x16x32_bf16(ah, bl, acc[nt], 0, 0, 0);
            acc[nt] = __builtin_amdgcn_mfma_f32_16x16x32_bf16(al, bh, acc[nt], 0, 0, 0);
        }
    }
    #pragma unroll
    for (int nt = 0; nt < 8; nt++){
        int c = nt*16 + ln;
        float bb = bsh[c];
        #pragma unroll
        for (int r = 0; r < 4; r++){
            Y[(rb + wave*16 + q*4 + r)*128 + c] = acc[nt][r] + bb;
        }
    }
    if (score){
        #pragma unroll
        for (int r = 0; r < 4; r++){
            float sp = 0.f;
            #pragma unroll
            for (int nt = 0; nt < 8; nt++){
                int c = nt*16 + ln;
                sp += (acc[nt][r] + bsh[c]) * qs[c];
            }
            sp += __shfl_xor(sp, 1);
            sp += __shfl_xor(sp, 2);
            sp += __shfl_xor(sp, 4);
            sp += __shfl_xor(sp, 8);
            if (ln == 0){
                int row = (int)rb + wave*16 + q*4 + r;
                score[row] = sp + b1 * (float)cntv[row];
            }
        }
    }
}

// ================= stage-1 prep body: CSR build + count + sort + degree-prop + dinv =================
// Pads [dc, ceil4(dc)) zeroed explicitly (no giant memset).
// smem layout: lcnt[0,2048) y[2048,6144) bins[6144,6400) permS[6400,8448)
__device__ void prep1_body(char* smem, int g, const int* __restrict__ ei,
        int* __restrict__ cnt, unsigned short* __restrict__ csrcp,
        int* __restrict__ permg, float* __restrict__ dinvg){
    int*   lcnt  = (int*)smem;
    float* y     = (float*)(smem + 2048);
    int*   bins  = (int*)(smem + 6144);
    int*   permS = (int*)(smem + 6400);
    int t = threadIdx.x, gbase = g*512;
    lcnt[t] = 0;
    if (t < 64) bins[t] = 0;
    __syncthreads();
    for (int i = t; i < EPG; i += 512){
        int e = g*EPG + i;
        int sv = ei[e] & 511;          // ids are g*512+local; 512-aligned -> &511 = local
        int d  = ei[E_ + e] & 511;
        int slot = atomicAdd(&lcnt[d], 1);
        if (slot < DEGMAX) csrcp[(size_t)(gbase + d)*DEGMAX + slot] = (unsigned short)sv;
    }
    __syncthreads();                   // csr (global, own block) + lcnt ready
    int rawc = lcnt[t];
    cnt[gbase + t] = rawc;             // GEMM score epilogue's node-strength term (unclamped)
    int dc = min(rawc, DEGMAX);
    {   // zero only the pad slots the quad loop reads: [dc, ceil4(dc))
        int e4 = (dc + 3) & ~3;
        for (int s2 = dc; s2 < e4; s2++) csrcp[(size_t)(gbase + t)*DEGMAX + s2] = 0;
    }
    atomicAdd(&bins[dc], 1);
    __syncthreads();
    if (t < 64){
        int v0 = bins[t], s = v0;
        #pragma unroll
        for (int off = 1; off < 64; off <<= 1){
            int n = __shfl_up(s, off);
            if (t >= off) s += n;
        }
        bins[t] = s - v0;              // exclusive prefix
    }
    __syncthreads();
    {
        int slot = atomicAdd(&bins[dc], 1);
        int pk = t | (dc << 16);
        permS[slot] = pk;
        permg[gbase + slot] = pk;
    }
    __syncthreads();
    int pk = permS[t];
    int pv = pk & 0xffff, pd = pk >> 16;
    y[pv] = 1.f;
    __syncthreads();
    float dacc = 1.f;
    int cur = 0;
    for (int l = 0; l < 4; l++){
        const float* la = &y[cur*512];
        float s = 0.f;
        int nq = (pd + 3) >> 2;
        const u16x4* cp = (const u16x4*)(csrcp + (size_t)(gbase + pv)*DEGMAX);
        u16x4 oc = cp[0];
        #pragma unroll 1
        for (int jq = 0; jq < nq; jq++){
            u16x4 ocn = cp[jq + 1];    // +8B over-read stays in workspace
            s += (la[(int)oc[0]] + la[(int)oc[1]]) + (la[(int)oc[2]] + la[(int)oc[3]]);
            oc = ocn;
        }
        if (nq) s -= (float)(nq*4 - pd) * la[0];
        y[(1^cur)*512 + pv] = s;
        dacc += s;
        __syncthreads();
        cur ^= 1;
    }
    dinvg[gbase + pv] = rsqrtf(fmaxf(dacc, 1e-12f));
}

// ================= merged launch: prep1 (blocks 0..127) || lump GEMM (blocks 128..639) =================
__global__ __launch_bounds__(512) void k_lump_prep(const float* __restrict__ x,
        const float* __restrict__ lumpW, const float* __restrict__ lumpb, float* __restrict__ A,
        const int* __restrict__ ei, int* __restrict__ cnt, unsigned short* __restrict__ csr1,
        int* __restrict__ perm1, float* __restrict__ dinv1){
    __shared__ __align__(16) char smem[70912];
    if (blockIdx.x < G_) prep1_body(smem, blockIdx.x, ei, cnt, csr1, perm1, dinv1);
    else gemm_body<8>(smem, blockIdx.x - G_, x, lumpW, lumpb, A,
                      nullptr, nullptr, nullptr, nullptr);
}

// ================= standalone GEMM (+score) =================
template<int WAVES>
__global__ __launch_bounds__(WAVES*64) void k_gemm_mfma(const float* __restrict__ X,
        const float* __restrict__ W, const float* __restrict__ bias, float* __restrict__ Y,
        const float* __restrict__ p, const float* __restrict__ beta,
        const int* __restrict__ cntv, float* __restrict__ score){
    __shared__ __align__(16) char smem[70912];
    gemm_body<WAVES>(smem, blockIdx.x, X, W, bias, Y, p, beta, cntv, score);
}

// ---------------- per-graph feature prop ----------------
// OUT = dinv * (sum_l A^l)(dinv * x). R15 tiling (1024 thr, fq=4, 128B row stride =
// LDS b128 issue floor). R20: CSR staged COMPACTED into LDS once per block (prefix
// scan over per-slot nq); level loop reads quads via 8-lane LDS broadcast -> the
// ~200cy global L2 latency leaves the per-iteration dependence chain. CSR global
// re-reads drop 4x.
// REGISTER HISTORY (DO NOT REPEAT): min-waves hints (R7/R14 launch_bounds(1024,8))
// force a 32-VGPR ceiling -> catastrophic spill. Hard budget 64 VGPR (2 blocks/CU
// at 16 waves needs 8 waves/SIMD * 64 = 512 = whole file). Watch occupancy ~18% +
// dur doubling = reg cliff -> revert.
template<int NPER, int L, int IT, bool SEL>
__global__ __launch_bounds__(1024)
void k_prop(const int* __restrict__ permg, const float* __restrict__ dinvg,
        const unsigned short* __restrict__ csrcp,
        const float* __restrict__ X, const int* __restrict__ selg,
        const float* __restrict__ thg, float* __restrict__ OUT){
    constexpr int QMAX = (EPG + 3*NPER)/4 + 4;
    constexpr int NW   = NPER/64;
    __shared__ __align__(16) float y[NPER*32];
    __shared__ float dinvs[NPER];
    __shared__ u16x4 csrl[QMAX];
    __shared__ unsigned short qoffS[NPER];
    __shared__ int wsumS[NW];
    int g = blockIdx.x, fq = blockIdx.y, gbase = g*NPER;
    int t = threadIdx.x;
    int f4 = (t & 7)*4;
    int fo = fq*32 + f4;
    if (t < NPER) dinvs[t] = dinvg[gbase + t];
    int pkr[IT];
    {
        int wv = t >> 6, gi = (t >> 3) & 7;
        #pragma unroll
        for (int it = 0; it < IT; it++){
            int ch = (it & 1) ? (15 - wv) : wv;
            pkr[it] = permg[gbase + (16*it + ch)*8 + gi];
        }
    }
    // ---- prefix scan of nq over sorted slots (slot t handled by thread t) ----
    int nqv = 0, pvv = 0;
    if (t < NPER){
        int pk2 = permg[gbase + t];
        pvv = pk2 & 0xffff;
        nqv = ((pk2 >> 16) + 3) >> 2;
    }
    int incl = nqv;
    #pragma unroll
    for (int off2 = 1; off2 < 64; off2 <<= 1){
        int n2 = __shfl_up(incl, off2);
        if ((t & 63) >= off2) incl += n2;
    }
    if (t < NPER && (t & 63) == 63) wsumS[t >> 6] = incl;
    __syncthreads();
    if (t == 0){
        int run = 0;
        #pragma unroll
        for (int w = 0; w < NW; w++){ int v2 = wsumS[w]; wsumS[w] = run; run += v2; }
    }
    __syncthreads();
    // ---- CSR stage (global -> compact LDS) ----
    if (t < NPER){
        int qo = incl - nqv + wsumS[t >> 6];
        qoffS[pvv] = (unsigned short)qo;
        const u16x4* gp = (const u16x4*)(csrcp + (size_t)(gbase + pvv)*DEGMAX);
        for (int j = 0; j < nqv; j++) csrl[qo + j] = gp[j];
    }
    // ---- X stage (scaled by dinv; SEL applies pooled gather * tanh) ----
    float4 acc[IT];
    #pragma unroll
    for (int it = 0; it < IT; it++){
        int v = pkr[it] & 0xffff;
        float d = dinvs[v];
        size_t row;
        if (SEL){
            row = (size_t)selg[gbase + v];
            d *= thg[gbase + v];
        } else {
            row = (size_t)(gbase + v);
        }
        float4 w = *(const float4*)&X[row*128 + fo];
        w.x*=d; w.y*=d; w.z*=d; w.w*=d;
        acc[it] = w;
        *(float4*)&y[v*32 + f4] = w;
    }
    __syncthreads();
    for (int l = 0; l < L; l++){
        float4 s[IT];
        #pragma unroll
        for (int it = 0; it < IT; it++){
            int pk = pkr[it];
            int v = pk & 0xffff;
            int c = pk >> 16;
            int nq = (c + 3) >> 2;
            const u16x4* cp = &csrl[(int)qoffS[v]];
            float4 ss = make_float4(0.f,0.f,0.f,0.f);
            u16x4 oc = cp[0];
            #pragma unroll 1
            for (int jq = 0; jq < nq; jq++){
                u16x4 ocn = cp[jq + 1];      // LDS prefetch; +1 pad quad in csrl
                float4 w0 = *(const float4*)&y[((int)oc[0])*32 + f4];
                float4 w1 = *(const float4*)&y[((int)oc[1])*32 + f4];
                float4 w2 = *(const float4*)&y[((int)oc[2])*32 + f4];
                float4 w3 = *(const float4*)&y[((int)oc[3])*32 + f4];
                ss.x += (w0.x + w1.x) + (w2.x + w3.x);
                ss.y += (w0.y + w1.y) + (w2.y + w3.y);
                ss.z += (w0.z + w1.z) + (w2.z + w3.z);
                ss.w += (w0.w + w1.w) + (w2.w + w3.w);
                oc = ocn;
            }
            if (nq){
                float fp = (float)(nq*4 - c);
                float4 z = *(const float4*)&y[f4];          // row 0 (broadcast)
                ss.x -= fp*z.x; ss.y -= fp*z.y; ss.z -= fp*z.z; ss.w -= fp*z.w;
            }
            s[it] = ss;
        }
        __syncthreads();
        #pragma unroll
        for (int it = 0; it < IT; it++){
            int v = pkr[it] & 0xffff;
            *(float4*)&y[v*32 + f4] = s[it];
            acc[it].x+=s[it].x; acc[it].y+=s[it].y; acc[it].z+=s[it].z; acc[it].w+=s[it].w;
        }
        __syncthreads();
    }
    #pragma unroll
    for (int it = 0; it < IT; it++){
        int v = pkr[it] & 0xffff;
        float d = dinvs[v];
        float4 w = acc[it];
        w.x*=d; w.y*=d; w.z*=d; w.w*=d;
        *(float4*)&OUT[(size_t)(gbase + v)*128 + fo] = w;
    }
}

// ---------------- pooling control: rank + sel/th emit + edge remap + next-stage prep ----------------
template<int NPER, bool BUILD>
__global__ __launch_bounds__(512) void k_pooltop(const float* __restrict__ score_in,
        const int* __restrict__ esrc_in, const int* __restrict__ edst_in,
        int* __restrict__ esrc_out, int* __restrict__ edst_out,
        int* __restrict__ cnt_next, unsigned short* __restrict__ csrcp,
        int* __restrict__ permg, float* __restrict__ dinvg,
        int* __restrict__ selg, float* __restrict__ thg){
    __shared__ __align__(16) float sc[NPER];
    __shared__ int  nid[NPER];
    __shared__ int  lcnt[NPER/2];
    __shared__ int  bins[64];
    __shared__ int  permS[NPER/2];
    const int K = NPER/2;
    int g = blockIdx.x, t = threadIdx.x, gbase = g*NPER;
    if (t < K) lcnt[t] = 0;
    if (t < 64) bins[t] = 0;
    if (t < NPER) sc[t] = score_in[gbase + t];
    __syncthreads();
    if (t < NPER){
        float s = sc[t];
        int rank = 0;
        const float4* sc4 = (const float4*)sc;
        #pragma unroll 8
        for (int j4 = 0; j4 < NPER/4; j4++){
            float4 v = sc4[j4];
            int j = j4*4;
            rank += (v.x > s) || (v.x == s && (j+0) < t);   // stable tie-break = lax.top_k
            rank += (v.y > s) || (v.y == s && (j+1) < t);
            rank += (v.z > s) || (v.z == s && (j+2) < t);
            rank += (v.w > s) || (v.w == s && (j+3) < t);
        }
        if (rank < K){
            nid[t] = g*K + rank;
            selg[g*K + rank] = gbase + t;       // source row in the conv-output buffer
            thg[g*K + rank]  = tanhf(s);
        } else nid[t] = -1;
    }
    __syncthreads();
    if (BUILD){
        for (int i = t; i < EPG; i += 512){
            int e = g*EPG + i;
            int d = edst_in[e];
            if (d < 0) continue;
            int s_ = esrc_in[e];
            int ns = nid[s_ - gbase], nd = nid[d - gbase];
            if ((ns | nd) < 0){ edst_out[e] = -1; }
            else {
                esrc_out[e] = ns; edst_out[e] = nd;
                int slot = atomicAdd(&lcnt[nd & (K-1)], 1);
                if (slot < DEGMAX) csrcp[(size_t)nd*DEGMAX + slot] = (unsigned short)(ns & (K-1));
            }
        }
        __syncthreads();               // csr (global, own block) + lcnt ready
        float* yd = sc;                // reuse: sc dead after rank; 2*K == NPER floats
        int rawc = 0, dc = 0;
        if (t < K){
            rawc = lcnt[t];
            cnt_next[g*K + t] = rawc;
            dc = min(rawc, DEGMAX);
            int e4 = (dc + 3) & ~3;    // zero pad slots the quad loop reads
            for (int s2 = dc; s2 < e4; s2++) csrcp[(size_t)(g*K + t)*DEGMAX + s2] = 0;
            atomicAdd(&bins[dc], 1);
        }
        __syncthreads();
        if (t < 64){
            int v0 = bins[t], s = v0;
            #pragma unroll
            for (int off = 1; off < 64; off <<= 1){
                int n = __shfl_up(s, off);
                if (t >= off) s += n;
            }
            bins[t] = s - v0;
        }
        __syncthreads();
        if (t < K){
            int slot = atomicAdd(&bins[dc], 1);
            permS[slot] = t | (dc << 16);
            permg[g*K + slot] = permS[slot];
        }
        __syncthreads();
        int pv = 0, pd = 0;
        if (t < K){
            int pk = permS[t];
            pv = pk & 0xffff; pd = pk >> 16;
            yd[pv] = 1.f;
        }
        __syncthreads();
        float dacc = 1.f;
        int cur = 0;
        for (int l = 0; l < 2; l++){
            if (t < K){
                const float* la = &yd[cur*K];
                float s = 0.f;
                int nq = (pd + 3) >> 2;
                const u16x4* cp = (const u16x4*)(csrcp + (size_t)(g*K + pv)*DEGMAX);
                u16x4 oc = cp[0];
                #pragma unroll 1
                for (int jq = 0; jq < nq; jq++){
                    u16x4 ocn = cp[jq + 1];
                    s += (la[(int)oc[0]] + la[(int)oc[1]]) + (la[(int)oc[2]] + la[(int)oc[3]]);
                    oc = ocn;
                }
                if (nq) s -= (float)(nq*4 - pd) * la[0];
                yd[(1^cur)*K + pv] = s;
                dacc += s;
            }
            __syncthreads();
            cur ^= 1;
        }
        if (t < K) dinvg[g*K + pv] = rsqrtf(fmaxf(dacc, 1e-12f));
    }
}

// ---------------- fused stage 3: per-graph conv3 GEMM + score + rank + mean + MLP ----------------
// Graph g's 128 rows = exactly 8 waves of GEMM. Y kept on-chip: written into the
// (dead-after-MFMA) W-staging LDS as [128][132] (pad kills the stride-128 same-bank
// column read). Deletes conv3's 4MB A-write + pool3_mean's read-back + 1 launch.
__global__ __launch_bounds__(512) void k_stage3(const float* __restrict__ X,
        const float* __restrict__ W, const float* __restrict__ bias,
        const float* __restrict__ p, const float* __restrict__ beta,
        const int* __restrict__ cntv,
        const float* __restrict__ W1, const float* __restrict__ b1,
        const float* __restrict__ W2, const float* __restrict__ b2,
        float* __restrict__ out){
    __shared__ __align__(16) char smem[70912];
    __shared__ float scs[128];
    __shared__ float thS[64];
    __shared__ int   selS[64];
    __shared__ float mr[128];
    short* wsh = (short*)smem;
    short* wsl = (short*)(smem + 34816);
    float* bsh = (float*)(smem + 69632);
    float* qs  = (float*)(smem + 70144);
    float* rednorm = (float*)(smem + 70656);
    int g = blockIdx.x, t = threadIdx.x;
    for (int e = t; e < 16384; e += 512){
        int k = e >> 7, n = e & 127;
        short hi, lo; split_bf16(W[e], hi, lo);
        wsh[n*136 + k] = hi; wsl[n*136 + k] = lo;
    }
    if (t < 128) bsh[t] = bias[t];
    if (t < 64){ float a = p[t], b = p[t+64]; rednorm[t] = a*a + b*b; }
    __syncthreads();
    if (t == 0){ float s = 0.f; for (int i = 0; i < 64; i++) s += rednorm[i]; rednorm[0] = sqrtf(s); }
    __syncthreads();
    if (t < 128) qs[t] = beta[0] * p[t] / rednorm[0];
    float b1v = beta[1];
    __syncthreads();
    int wave = t >> 6, lane = t & 63;
    int ln = lane & 15, q = lane >> 4;
    const float* xrow = &X[((size_t)g*128 + wave*16 + ln)*128 + q*8];
    f32x4 acc[8];
    #pragma unroll
    for (int i = 0; i < 8; i++) acc[i] = (f32x4){0.f,0.f,0.f,0.f};
    #pragma unroll
    for (int kc = 0; kc < 4; kc++){
        float4 xa = *(const float4*)(xrow + kc*32);
        float4 xb = *(const float4*)(xrow + kc*32 + 4);
        bf16x8 ah, al; short hi, lo;
        split_bf16(xa.x, hi, lo); ah[0]=hi; al[0]=lo;
        split_bf16(xa.y, hi, lo); ah[1]=hi; al[1]=lo;
        split_bf16(xa.z, hi, lo); ah[2]=hi; al[2]=lo;
        split_bf16(xa.w, hi, lo); ah[3]=hi; al[3]=lo;
        split_bf16(xb.x, hi, lo); ah[4]=hi; al[4]=lo;
        split_bf16(xb.y, hi, lo); ah[5]=hi; al[5]=lo;
        split_bf16(xb.z, hi, lo); ah[6]=hi; al[6]=lo;
        split_bf16(xb.w, hi, lo); ah[7]=hi; al[7]=lo;
        #pragma unroll
        for (int nt = 0; nt < 8; nt++){
            int wo = (nt*16 + ln)*136 + kc*32 + q*8;
            bf16x8 bh = *(const bf16x8*)&wsh[wo];
            bf16x8 bl = *(const bf16x8*)&wsl[wo];
            acc[nt] = __builtin_amdgcn_mfma_f32_16x16x32_bf16(ah, bh, acc[nt], 0, 0, 0);
            acc[nt] = __builtin_amdgcn_mfma_f32_16x16x32_bf16(ah, bl, acc[nt], 0, 0, 0);
            acc[nt] = __builtin_amdgcn_mfma_f32_16x16x32_bf16(al, bh, acc[nt], 0, 0, 0);
        }
    }
    // score from regs
    #pragma unroll
    for (int r = 0; r < 4; r++){
        float sp = 0.f;
        #pragma unroll
        for (int nt = 0; nt < 8; nt++){
            int c = nt*16 + ln;
            sp += (acc[nt][r] + bsh[c]) * qs[c];
        }
        sp += __shfl_xor(sp, 1);
        sp += __shfl_xor(sp, 2);
        sp += __shfl_xor(sp, 4);
        sp += __shfl_xor(sp, 8);
        if (ln == 0){
            int rl = wave*16 + q*4 + r;
            scs[rl] = sp + b1v * (float)cntv[g*128 + rl];
        }
    }
    __syncthreads();                       // wsh/wsl reads done -> safe to overwrite
    float* Yl = (float*)smem;              // [128][132]
    #pragma unroll
    for (int nt = 0; nt < 8; nt++){
        int c = nt*16 + ln;
        float bb = bsh[c];
        #pragma unroll
        for (int r = 0; r < 4; r++){
            Yl[(wave*16 + q*4 + r)*132 + c] = acc[nt][r] + bb;
        }
    }
    __syncthreads();
    if (t < 128){
        float s = scs[t];
        int rank = 0;
        const float4* sc4 = (const float4*)scs;
        #pragma unroll 8
        for (int j4 = 0; j4 < 32; j4++){
            float4 v = sc4[j4];
            int j = j4*4;
            rank += (v.x > s) || (v.x == s && (j+0) < t);   // stable tie-break = lax.top_k
            rank += (v.y > s) || (v.y == s && (j+1) < t);
            rank += (v.z > s) || (v.z == s && (j+2) < t);
            rank += (v.w > s) || (v.w == s && (j+3) < t);
        }
        if (rank < 64){ selS[rank] = t; thS[rank] = tanhf(s); }
    }
    __syncthreads();
    if (t < 128){
        float s = 0.f;
        #pragma unroll 8
        for (int r = 0; r < 64; r++) s += Yl[selS[r]*132 + t] * thS[r];
        mr[t] = s * (1.f/64.f);
    }
    __syncthreads();
    if (t < 64){
        float a = b1[t];
        #pragma unroll 8
        for (int k = 0; k < 128; k++) a += mr[k]*W1[k*64 + t];
        a = fmaxf(a, 0.f);
        float r = a * W2[t];
        #pragma unroll
        for (int off = 32; off > 0; off >>= 1) r += __shfl_down(r, off);
        if (t == 0) out[g] = r + b2[0];
    }
}

// ---------------- driver: 9 launches ----------------
extern "C" void kernel_launch(void* const* d_in, const int* in_sizes, int n_in,
                              void* d_out, int out_size, void* d_ws, size_t ws_size,
                              hipStream_t stream){
    (void)in_sizes; (void)n_in; (void)out_size; (void)ws_size;
    const float* x     = (const float*)d_in[0];
    const int*   ei    = (const int*)d_in[1];
    const float* lumpW = (const float*)d_in[3];
    const float* lumpb = (const float*)d_in[4];
    const float* convW[3]    = {(const float*)d_in[5], (const float*)d_in[7], (const float*)d_in[9]};
    const float* convB[3]    = {(const float*)d_in[6], (const float*)d_in[8], (const float*)d_in[10]};
    const float* poolP[3]    = {(const float*)d_in[11], (const float*)d_in[13], (const float*)d_in[15]};
    const float* poolBeta[3] = {(const float*)d_in[12], (const float*)d_in[14], (const float*)d_in[16]};
    const float* lin1W = (const float*)d_in[17];
    const float* lin1b = (const float*)d_in[18];
    const float* lin2W = (const float*)d_in[19];
    const float* lin2b = (const float*)d_in[20];
    float* out = (float*)d_out;

    char* w8 = (char*)d_ws;
    size_t off = 0;
    auto alloc = [&](size_t bytes)->char*{
        char* p = w8 + off; off += (bytes + 255) & ~(size_t)255; return p;
    };
    float* A     = (float*)alloc((size_t)65536*128*4);
    float* Bb    = (float*)alloc((size_t)65536*128*4);
    int*   srcA  = (int*)alloc((size_t)E_*4);
    int*   dstA  = (int*)alloc((size_t)E_*4);
    unsigned short* csr1 = (unsigned short*)alloc((size_t)65536*DEGMAX*2);
    unsigned short* csr2 = (unsigned short*)alloc((size_t)32768*DEGMAX*2);
    unsigned short* csr3 = (unsigned short*)alloc((size_t)16384*DEGMAX*2);
    int*   cntA  = (int*)alloc((size_t)(65536+32768+16384)*4);
    int*   cnt1 = cntA, *cnt2 = cntA + 65536, *cnt3 = cntA + 98304;
    int*   perm1 = (int*)alloc((size_t)65536*4);
    int*   perm2 = (int*)alloc((size_t)32768*4);
    int*   perm3 = (int*)alloc((size_t)16384*4);
    float* dinv1 = (float*)alloc((size_t)65536*4);
    float* dinv2 = (float*)alloc((size_t)32768*4);
    float* dinv3 = (float*)alloc((size_t)16384*4);
    float* score1 = (float*)alloc((size_t)65536*4);
    float* score2 = (float*)alloc((size_t)32768*4);
    int*   sel2  = (int*)alloc((size_t)32768*4);
    int*   sel3  = (int*)alloc((size_t)16384*4);
    float* th2   = (float*)alloc((size_t)32768*4);
    float* th3   = (float*)alloc((size_t)16384*4);

    // ----- prep1 (blocks 0..127) || lump GEMM (blocks 128..639), no memset -----
    k_lump_prep<<<G_ + 512, 512, 0, stream>>>(x, lumpW, lumpb, A, ei, cnt1, csr1, perm1, dinv1);

    // ----- stage 1: conv1 (L=4, nper=512), pool -> 256/graph -----
    k_prop<512,4,4,false><<<dim3(G_,4), 1024, 0, stream>>>(perm1, dinv1, csr1, A,
            nullptr, nullptr, Bb);
    k_gemm_mfma<8><<<512, 512, 0, stream>>>(Bb, convW[0], convB[0], A,
            poolP[0], poolBeta[0], cnt1, score1);
    k_pooltop<512,true><<<G_, 512, 0, stream>>>(score1, ei, ei + E_, srcA, dstA,
            cnt2, csr2, perm2, dinv2, sel2, th2);

    // ----- stage 2: conv2 (L=2, nper=256), pool -> 128/graph -----
    k_prop<256,2,2,true><<<dim3(G_,4), 1024, 0, stream>>>(perm2, dinv2, csr2, A,
            sel2, th2, Bb);
    k_gemm_mfma<8><<<256, 512, 0, stream>>>(Bb, convW[1], convB[1], A,
            poolP[1], poolBeta[1], cnt2, score2);
    k_pooltop<256,true><<<G_, 512, 0, stream>>>(score2, srcA, dstA, srcA, dstA,
            cnt3, csr3, perm3, dinv3, sel3, th3);

    // ----- stage 3: conv3 (L=2, nper=128) then fused conv3-gemm+pool+mean+MLP -----
    k_prop<128,2,1,true><<<dim3(G_,4), 1024, 0, stream>>>(perm3, dinv3, csr3, A,
            sel3, th3, Bb);
    k_stage3<<<G_, 512, 0, stream>>>(Bb, convW[2], convB[2],
            poolP[2], poolBeta[2], cnt3, lin1W, lin1b, lin2W, lin2b, out);
}

// Round 8
// 276.932 us; speedup vs baseline: 1.3124x; 1.0760x over previous
//
#include <hip/hip_runtime.h>
#include <math.h>

#define G_     128
#define E_     524288
#define EPG    4096
#define DEGMAX 48

typedef __attribute__((ext_vector_type(8))) short bf16x8;
typedef __attribute__((ext_vector_type(4))) float f32x4;
typedef __attribute__((ext_vector_type(4))) unsigned short u16x4;

__device__ inline void split_bf16(float x, short& hi, short& lo){
    unsigned u = __float_as_uint(x);
    hi = (short)(u >> 16);
    float hf = __uint_as_float(u & 0xffff0000u);
    unsigned r = __float_as_uint(x - hf);
    lo = (short)(r >> 16);
}

// ================= shared GEMM body: Y = X(Mx128) @ W(128x128) + bias (+score) =================
// smem layout: wsh[0,34816) wsl[34816,69632) bsh[69632,70144) qs[70144,70656) red[70656,70912)
template<int WAVES>
__device__ void gemm_body(char* smem, int bid, const float* __restrict__ X,
        const float* __restrict__ W, const float* __restrict__ bias, float* __restrict__ Y,
        const float* __restrict__ p, const float* __restrict__ beta,
        const int* __restrict__ cntv, float* __restrict__ score){
    short* wsh = (short*)smem;
    short* wsl = (short*)(smem + 34816);
    float* bsh = (float*)(smem + 69632);
    float* qs  = (float*)(smem + 70144);
    float* rednorm = (float*)(smem + 70656);
    const int NT = WAVES*64;
    int t = threadIdx.x;
    for (int e = t; e < 16384; e += NT){
        int k = e >> 7, n = e & 127;
        short hi, lo; split_bf16(W[e], hi, lo);
        wsh[n*136 + k] = hi; wsl[n*136 + k] = lo;
    }
    if (t < 128) bsh[t] = bias[t];
    if (score && t < 64){ float a = p[t], b = p[t+64]; rednorm[t] = a*a + b*b; }
    __syncthreads();
    float b1 = 0.f;
    if (score){
        if (t == 0){ float s = 0.f; for (int i = 0; i < 64; i++) s += rednorm[i]; rednorm[0] = sqrtf(s); }
        __syncthreads();
        if (t < 128) qs[t] = beta[0] * p[t] / rednorm[0];
        b1 = beta[1];
        __syncthreads();
    }
    int wave = t >> 6, lane = t & 63;
    int ln = lane & 15, q = lane >> 4;
    size_t rb = (size_t)bid * (WAVES*16);
    const float* xrow = &X[(rb + wave*16 + ln)*128 + q*8];
    f32x4 acc[8];
    #pragma unroll
    for (int i = 0; i < 8; i++) acc[i] = (f32x4){0.f,0.f,0.f,0.f};
    #pragma unroll
    for (int kc = 0; kc < 4; kc++){
        float4 xa = *(const float4*)(xrow + kc*32);
        float4 xb = *(const float4*)(xrow + kc*32 + 4);
        bf16x8 ah, al; short hi, lo;
        split_bf16(xa.x, hi, lo); ah[0]=hi; al[0]=lo;
        split_bf16(xa.y, hi, lo); ah[1]=hi; al[1]=lo;
        split_bf16(xa.z, hi, lo); ah[2]=hi; al[2]=lo;
        split_bf16(xa.w, hi, lo); ah[3]=hi; al[3]=lo;
        split_bf16(xb.x, hi, lo); ah[4]=hi; al[4]=lo;
        split_bf16(xb.y, hi, lo); ah[5]=hi; al[5]=lo;
        split_bf16(xb.z, hi, lo); ah[6]=hi; al[6]=lo;
        split_bf16(xb.w, hi, lo); ah[7]=hi; al[7]=lo;
        #pragma unroll
        for (int nt = 0; nt < 8; nt++){
            int wo = (nt*16 + ln)*136 + kc*32 + q*8;
            bf16x8 bh = *(const bf16x8*)&wsh[wo];
            bf16x8 bl = *(const bf16x8*)&wsl[wo];
            acc[nt] = __builtin_amdgcn_mfma_f32_16x16x32_bf16(ah, bh, acc[nt], 0, 0, 0);
            acc[nt] = __builtin_amdgcn_mfma_f32_16x16x32_bf16(ah, bl, acc[nt], 0, 0, 0);
            acc[nt] = __builtin_amdgcn_mfma_f32_16x16x32_bf16(al, bh, acc[nt], 0, 0, 0);
        }
    }
    #pragma unroll
    for (int nt = 0; nt < 8; nt++){
        int c = nt*16 + ln;
        float bb = bsh[c];
        #pragma unroll
        for (int r = 0; r < 4; r++){
            Y[(rb + wave*16 + q*4 + r)*128 + c] = acc[nt][r] + bb;
        }
    }
    if (score){
        #pragma unroll
        for (int r = 0; r < 4; r++){
            float sp = 0.f;
            #pragma unroll
            for (int nt = 0; nt < 8; nt++){
                int c = nt*16 + ln;
                sp += (acc[nt][r] + bsh[c]) * qs[c];
            }
            sp += __shfl_xor(sp, 1);
            sp += __shfl_xor(sp, 2);
            sp += __shfl_xor(sp, 4);
            sp += __shfl_xor(sp, 8);
            if (ln == 0){
                int row = (int)rb + wave*16 + q*4 + r;
                score[row] = sp + b1 * (float)cntv[row];
            }
        }
    }
}

// ================= standalone GEMM (+score) =================
template<int WAVES>
__global__ __launch_bounds__(WAVES*64) void k_gemm_mfma(const float* __restrict__ X,
        const float* __restrict__ W, const float* __restrict__ bias, float* __restrict__ Y,
        const float* __restrict__ p, const float* __restrict__ beta,
        const int* __restrict__ cntv, float* __restrict__ score){
    __shared__ __align__(16) char smem[70912];
    gemm_body<WAVES>(smem, blockIdx.x, X, W, bias, Y, p, beta, cntv, score);
}

// ================= stage-1 prep: LDS-built CSR + coalesced writeout + sort + degree-prop =================
// R21: CSR built entirely in LDS (4096 scattered global u16 RMW stores -> ~2cy LDS
// stores), written to global COALESCED (u32, 24/thread), degree-prop reads LDS.
// Pads stay 0 from the LDS memset -> no global memset / pad-zero loop needed.
__global__ __launch_bounds__(512) void k_prep1(const int* __restrict__ ei,
        int* __restrict__ cnt, unsigned short* __restrict__ csrcp,
        int* __restrict__ permg, float* __restrict__ dinvg){
    __shared__ int   lcnt[512];
    __shared__ __align__(16) unsigned short csrS[512*DEGMAX + 8];  // 49168 B (+8B prefetch pad)
    __shared__ float y[1024];          // degree ping-pong
    __shared__ int   bins[64];
    __shared__ int   permS[512];
    int g = blockIdx.x, t = threadIdx.x, gbase = g*512;
    lcnt[t] = 0;
    if (t < 64) bins[t] = 0;
    unsigned* c32 = (unsigned*)csrS;
    for (int i = t; i < 512*DEGMAX/2 + 4; i += 512) c32[i] = 0;
    __syncthreads();
    for (int i = t; i < EPG; i += 512){
        int e = g*EPG + i;
        int sv = ei[e] & 511;          // ids are g*512+local; 512-aligned -> &511 = local
        int d  = ei[E_ + e] & 511;
        int slot = atomicAdd(&lcnt[d], 1);
        if (slot < DEGMAX) csrS[d*DEGMAX + slot] = (unsigned short)sv;
    }
    __syncthreads();                   // csrS + lcnt ready
    {   // coalesced CSR writeout (k_prop reads it from global)
        unsigned* dst = (unsigned*)(csrcp + (size_t)gbase*DEGMAX);
        for (int i = t; i < 512*DEGMAX/2; i += 512) dst[i] = c32[i];
    }
    int rawc = lcnt[t];
    cnt[gbase + t] = rawc;             // GEMM score epilogue's node-strength term (unclamped)
    int dc = min(rawc, DEGMAX);
    atomicAdd(&bins[dc], 1);
    __syncthreads();
    if (t < 64){
        int v0 = bins[t], s = v0;
        #pragma unroll
        for (int off = 1; off < 64; off <<= 1){
            int n = __shfl_up(s, off);
            if (t >= off) s += n;
        }
        bins[t] = s - v0;              // exclusive prefix
    }
    __syncthreads();
    {
        int slot = atomicAdd(&bins[dc], 1);
        int pk = t | (dc << 16);
        permS[slot] = pk;
        permg[gbase + slot] = pk;
    }
    __syncthreads();
    int pk = permS[t];
    int pv = pk & 0xffff, pd = pk >> 16;
    y[pv] = 1.f;
    __syncthreads();
    float dacc = 1.f;
    int cur = 0;
    for (int l = 0; l < 4; l++){
        const float* la = &y[cur*512];
        float s = 0.f;
        int nq = (pd + 3) >> 2;
        const u16x4* cp = (const u16x4*)(csrS + pv*DEGMAX);   // LDS, 96B row stride
        u16x4 oc = cp[0];
        #pragma unroll 1
        for (int jq = 0; jq < nq; jq++){
            u16x4 ocn = cp[jq + 1];    // +8B over-read lands in csrS pad
            s += (la[(int)oc[0]] + la[(int)oc[1]]) + (la[(int)oc[2]] + la[(int)oc[3]]);
            oc = ocn;
        }
        if (nq) s -= (float)(nq*4 - pd) * la[0];
        y[(1^cur)*512 + pv] = s;
        dacc += s;
        __syncthreads();
        cur ^= 1;
    }
    dinvg[gbase + pv] = rsqrtf(fmaxf(dacc, 1e-12f));
}

// ---------------- per-graph feature prop (R19 form: global CSR + 1-deep prefetch) ----------------
// OUT = dinv * (sum_l A^l)(dinv * x). R15 tiling (1024 thr, fq=4, 128B row stride =
// LDS b128 issue floor; 64B stride doubled conflicts in R16). R20's CSR-LDS staging
// was NEUTRAL-NEGATIVE (45.0 vs 43.0) -> reverted; the 1-deep prefetch + 32-wave TLP
// already hides CSR global latency.
// REGISTER HISTORY (DO NOT REPEAT): min-waves hints (R7/R14 launch_bounds(1024,8))
// force a 32-VGPR ceiling -> catastrophic scratch spill (FETCH 20->160MB).
template<int NPER, int L, int IT, bool SEL>
__global__ __launch_bounds__(1024)
void k_prop(const int* __restrict__ permg, const float* __restrict__ dinvg,
        const unsigned short* __restrict__ csrcp,
        const float* __restrict__ X, const int* __restrict__ selg,
        const float* __restrict__ thg, float* __restrict__ OUT){
    __shared__ __align__(16) float y[NPER*32];
    __shared__ float dinvs[NPER];
    int g = blockIdx.x, fq = blockIdx.y, gbase = g*NPER;
    int t = threadIdx.x;
    int f4 = (t & 7)*4;
    int fo = fq*32 + f4;
    if (t < NPER) dinvs[t] = dinvg[gbase + t];
    int pkr[IT];
    {
        int wv = t >> 6, gi = (t >> 3) & 7;
        #pragma unroll
        for (int it = 0; it < IT; it++){
            int ch = (it & 1) ? (15 - wv) : wv;
            pkr[it] = permg[gbase + (16*it + ch)*8 + gi];
        }
    }
    __syncthreads();
    float4 acc[IT];
    #pragma unroll
    for (int it = 0; it < IT; it++){
        int v = pkr[it] & 0xffff;
        float d = dinvs[v];
        size_t row;
        if (SEL){
            row = (size_t)selg[gbase + v];
            d *= thg[gbase + v];
        } else {
            row = (size_t)(gbase + v);
        }
        float4 w = *(const float4*)&X[row*128 + fo];
        w.x*=d; w.y*=d; w.z*=d; w.w*=d;
        acc[it] = w;
        *(float4*)&y[v*32 + f4] = w;
    }
    __syncthreads();
    for (int l = 0; l < L; l++){
        float4 s[IT];
        #pragma unroll
        for (int it = 0; it < IT; it++){
            int pk = pkr[it];
            int c = pk >> 16;
            int nq = (c + 3) >> 2;
            const u16x4* cp = (const u16x4*)(csrcp + (size_t)(gbase + (pk & 0xffff))*DEGMAX);
            float4 ss = make_float4(0.f,0.f,0.f,0.f);
            u16x4 oc = cp[0];
            #pragma unroll 1
            for (int jq = 0; jq < nq; jq++){
                u16x4 ocn = cp[jq + 1];
                float4 w0 = *(const float4*)&y[((int)oc[0])*32 + f4];
                float4 w1 = *(const float4*)&y[((int)oc[1])*32 + f4];
                float4 w2 = *(const float4*)&y[((int)oc[2])*32 + f4];
                float4 w3 = *(const float4*)&y[((int)oc[3])*32 + f4];
                ss.x += (w0.x + w1.x) + (w2.x + w3.x);
                ss.y += (w0.y + w1.y) + (w2.y + w3.y);
                ss.z += (w0.z + w1.z) + (w2.z + w3.z);
                ss.w += (w0.w + w1.w) + (w2.w + w3.w);
                oc = ocn;
            }
            if (nq){
                float fp = (float)(nq*4 - c);
                float4 z = *(const float4*)&y[f4];          // row 0 (broadcast)
                ss.x -= fp*z.x; ss.y -= fp*z.y; ss.z -= fp*z.z; ss.w -= fp*z.w;
            }
            s[it] = ss;
        }
        __syncthreads();
        #pragma unroll
        for (int it = 0; it < IT; it++){
            int v = pkr[it] & 0xffff;
            *(float4*)&y[v*32 + f4] = s[it];
            acc[it].x+=s[it].x; acc[it].y+=s[it].y; acc[it].z+=s[it].z; acc[it].w+=s[it].w;
        }
        __syncthreads();
    }
    #pragma unroll
    for (int it = 0; it < IT; it++){
        int v = pkr[it] & 0xffff;
        float d = dinvs[v];
        float4 w = acc[it];
        w.x*=d; w.y*=d; w.z*=d; w.w*=d;
        *(float4*)&OUT[(size_t)(gbase + v)*128 + fo] = w;
    }
}

// ---------------- pooling control: rank + sel/th emit + edge remap + next-stage prep ----------------
template<int NPER, bool BUILD>
__global__ __launch_bounds__(512) void k_pooltop(const float* __restrict__ score_in,
        const int* __restrict__ esrc_in, const int* __restrict__ edst_in,
        int* __restrict__ esrc_out, int* __restrict__ edst_out,
        int* __restrict__ cnt_next, unsigned short* __restrict__ csrcp,
        int* __restrict__ permg, float* __restrict__ dinvg,
        int* __restrict__ selg, float* __restrict__ thg){
    __shared__ __align__(16) float sc[NPER];
    __shared__ int  nid[NPER];
    __shared__ int  lcnt[NPER/2];
    __shared__ int  bins[64];
    __shared__ int  permS[NPER/2];
    const int K = NPER/2;
    int g = blockIdx.x, t = threadIdx.x, gbase = g*NPER;
    if (t < K) lcnt[t] = 0;
    if (t < 64) bins[t] = 0;
    if (t < NPER) sc[t] = score_in[gbase + t];
    __syncthreads();
    if (t < NPER){
        float s = sc[t];
        int rank = 0;
        const float4* sc4 = (const float4*)sc;
        #pragma unroll 8
        for (int j4 = 0; j4 < NPER/4; j4++){
            float4 v = sc4[j4];
            int j = j4*4;
            rank += (v.x > s) || (v.x == s && (j+0) < t);   // stable tie-break = lax.top_k
            rank += (v.y > s) || (v.y == s && (j+1) < t);
            rank += (v.z > s) || (v.z == s && (j+2) < t);
            rank += (v.w > s) || (v.w == s && (j+3) < t);
        }
        if (rank < K){
            nid[t] = g*K + rank;
            selg[g*K + rank] = gbase + t;       // source row in the conv-output buffer
            thg[g*K + rank]  = tanhf(s);
        } else nid[t] = -1;
    }
    __syncthreads();
    if (BUILD){
        for (int i = t; i < EPG; i += 512){
            int e = g*EPG + i;
            int d = edst_in[e];
            if (d < 0) continue;
            int s_ = esrc_in[e];
            int ns = nid[s_ - gbase], nd = nid[d - gbase];
            if ((ns | nd) < 0){ edst_out[e] = -1; }
            else {
                esrc_out[e] = ns; edst_out[e] = nd;
                int slot = atomicAdd(&lcnt[nd & (K-1)], 1);
                if (slot < DEGMAX) csrcp[(size_t)nd*DEGMAX + slot] = (unsigned short)(ns & (K-1));
            }
        }
        __syncthreads();               // csr (global, own block) + lcnt ready
        float* yd = sc;                // reuse: sc dead after rank; 2*K == NPER floats
        int rawc = 0, dc = 0;
        if (t < K){
            rawc = lcnt[t];
            cnt_next[g*K + t] = rawc;
            dc = min(rawc, DEGMAX);
            int e4 = (dc + 3) & ~3;    // zero pad slots the quad loop reads
            for (int s2 = dc; s2 < e4; s2++) csrcp[(size_t)(g*K + t)*DEGMAX + s2] = 0;
            atomicAdd(&bins[dc], 1);
        }
        __syncthreads();
        if (t < 64){
            int v0 = bins[t], s = v0;
            #pragma unroll
            for (int off = 1; off < 64; off <<= 1){
                int n = __shfl_up(s, off);
                if (t >= off) s += n;
            }
            bins[t] = s - v0;
        }
        __syncthreads();
        if (t < K){
            int slot = atomicAdd(&bins[dc], 1);
            permS[slot] = t | (dc << 16);
            permg[g*K + slot] = permS[slot];
        }
        __syncthreads();
        int pv = 0, pd = 0;
        if (t < K){
            int pk = permS[t];
            pv = pk & 0xffff; pd = pk >> 16;
            yd[pv] = 1.f;
        }
        __syncthreads();
        float dacc = 1.f;
        int cur = 0;
        for (int l = 0; l < 2; l++){
            if (t < K){
                const float* la = &yd[cur*K];
                float s = 0.f;
                int nq = (pd + 3) >> 2;
                const u16x4* cp = (const u16x4*)(csrcp + (size_t)(g*K + pv)*DEGMAX);
                u16x4 oc = cp[0];
                #pragma unroll 1
                for (int jq = 0; jq < nq; jq++){
                    u16x4 ocn = cp[jq + 1];
                    s += (la[(int)oc[0]] + la[(int)oc[1]]) + (la[(int)oc[2]] + la[(int)oc[3]]);
                    oc = ocn;
                }
                if (nq) s -= (float)(nq*4 - pd) * la[0];
                yd[(1^cur)*K + pv] = s;
                dacc += s;
            }
            __syncthreads();
            cur ^= 1;
        }
        if (t < K) dinvg[g*K + pv] = rsqrtf(fmaxf(dacc, 1e-12f));
    }
}

// ---------------- fused stage 3: per-graph conv3 GEMM + score + rank + mean + MLP ----------------
__global__ __launch_bounds__(512) void k_stage3(const float* __restrict__ X,
        const float* __restrict__ W, const float* __restrict__ bias,
        const float* __restrict__ p, const float* __restrict__ beta,
        const int* __restrict__ cntv,
        const float* __restrict__ W1, const float* __restrict__ b1,
        const float* __restrict__ W2, const float* __restrict__ b2,
        float* __restrict__ out){
    __shared__ __align__(16) char smem[70912];
    __shared__ float scs[128];
    __shared__ float thS[64];
    __shared__ int   selS[64];
    __shared__ float mr[128];
    short* wsh = (short*)smem;
    short* wsl = (short*)(smem + 34816);
    float* bsh = (float*)(smem + 69632);
    float* qs  = (float*)(smem + 70144);
    float* rednorm = (float*)(smem + 70656);
    int g = blockIdx.x, t = threadIdx.x;
    for (int e = t; e < 16384; e += 512){
        int k = e >> 7, n = e & 127;
        short hi, lo; split_bf16(W[e], hi, lo);
        wsh[n*136 + k] = hi; wsl[n*136 + k] = lo;
    }
    if (t < 128) bsh[t] = bias[t];
    if (t < 64){ float a = p[t], b = p[t+64]; rednorm[t] = a*a + b*b; }
    __syncthreads();
    if (t == 0){ float s = 0.f; for (int i = 0; i < 64; i++) s += rednorm[i]; rednorm[0] = sqrtf(s); }
    __syncthreads();
    if (t < 128) qs[t] = beta[0] * p[t] / rednorm[0];
    float b1v = beta[1];
    __syncthreads();
    int wave = t >> 6, lane = t & 63;
    int ln = lane & 15, q = lane >> 4;
    const float* xrow = &X[((size_t)g*128 + wave*16 + ln)*128 + q*8];
    f32x4 acc[8];
    #pragma unroll
    for (int i = 0; i < 8; i++) acc[i] = (f32x4){0.f,0.f,0.f,0.f};
    #pragma unroll
    for (int kc = 0; kc < 4; kc++){
        float4 xa = *(const float4*)(xrow + kc*32);
        float4 xb = *(const float4*)(xrow + kc*32 + 4);
        bf16x8 ah, al; short hi, lo;
        split_bf16(xa.x, hi, lo); ah[0]=hi; al[0]=lo;
        split_bf16(xa.y, hi, lo); ah[1]=hi; al[1]=lo;
        split_bf16(xa.z, hi, lo); ah[2]=hi; al[2]=lo;
        split_bf16(xa.w, hi, lo); ah[3]=hi; al[3]=lo;
        split_bf16(xb.x, hi, lo); ah[4]=hi; al[4]=lo;
        split_bf16(xb.y, hi, lo); ah[5]=hi; al[5]=lo;
        split_bf16(xb.z, hi, lo); ah[6]=hi; al[6]=lo;
        split_bf16(xb.w, hi, lo); ah[7]=hi; al[7]=lo;
        #pragma unroll
        for (int nt = 0; nt < 8; nt++){
            int wo = (nt*16 + ln)*136 + kc*32 + q*8;
            bf16x8 bh = *(const bf16x8*)&wsh[wo];
            bf16x8 bl = *(const bf16x8*)&wsl[wo];
            acc[nt] = __builtin_amdgcn_mfma_f32_16x16x32_bf16(ah, bh, acc[nt], 0, 0, 0);
            acc[nt] = __builtin_amdgcn_mfma_f32_16x16x32_bf16(ah, bl, acc[nt], 0, 0, 0);
            acc[nt] = __builtin_amdgcn_mfma_f32_16x16x32_bf16(al, bh, acc[nt], 0, 0, 0);
        }
    }
    // score from regs
    #pragma unroll
    for (int r = 0; r < 4; r++){
        float sp = 0.f;
        #pragma unroll
        for (int nt = 0; nt < 8; nt++){
            int c = nt*16 + ln;
            sp += (acc[nt][r] + bsh[c]) * qs[c];
        }
        sp += __shfl_xor(sp, 1);
        sp += __shfl_xor(sp, 2);
        sp += __shfl_xor(sp, 4);
        sp += __shfl_xor(sp, 8);
        if (ln == 0){
            int rl = wave*16 + q*4 + r;
            scs[rl] = sp + b1v * (float)cntv[g*128 + rl];
        }
    }
    __syncthreads();                       // wsh/wsl reads done -> safe to overwrite
    float* Yl = (float*)smem;              // [128][132]
    #pragma unroll
    for (int nt = 0; nt < 8; nt++){
        int c = nt*16 + ln;
        float bb = bsh[c];
        #pragma unroll
        for (int r = 0; r < 4; r++){
            Yl[(wave*16 + q*4 + r)*132 + c] = acc[nt][r] + bb;
        }
    }
    __syncthreads();
    if (t < 128){
        float s = scs[t];
        int rank = 0;
        const float4* sc4 = (const float4*)scs;
        #pragma unroll 8
        for (int j4 = 0; j4 < 32; j4++){
            float4 v = sc4[j4];
            int j = j4*4;
            rank += (v.x > s) || (v.x == s && (j+0) < t);   // stable tie-break = lax.top_k
            rank += (v.y > s) || (v.y == s && (j+1) < t);
            rank += (v.z > s) || (v.z == s && (j+2) < t);
            rank += (v.w > s) || (v.w == s && (j+3) < t);
        }
        if (rank < 64){ selS[rank] = t; thS[rank] = tanhf(s); }
    }
    __syncthreads();
    if (t < 128){
        float s = 0.f;
        #pragma unroll 8
        for (int r = 0; r < 64; r++) s += Yl[selS[r]*132 + t] * thS[r];
        mr[t] = s * (1.f/64.f);
    }
    __syncthreads();
    if (t < 64){
        float a = b1[t];
        #pragma unroll 8
        for (int k = 0; k < 128; k++) a += mr[k]*W1[k*64 + t];
        a = fmaxf(a, 0.f);
        float r = a * W2[t];
        #pragma unroll
        for (int off = 32; off > 0; off >>= 1) r += __shfl_down(r, off);
        if (t == 0) out[g] = r + b2[0];
    }
}

// ---------------- driver: 10 launches ----------------
extern "C" void kernel_launch(void* const* d_in, const int* in_sizes, int n_in,
                              void* d_out, int out_size, void* d_ws, size_t ws_size,
                              hipStream_t stream){
    (void)in_sizes; (void)n_in; (void)out_size; (void)ws_size;
    const float* x     = (const float*)d_in[0];
    const int*   ei    = (const int*)d_in[1];
    const float* lumpW = (const float*)d_in[3];
    const float* lumpb = (const float*)d_in[4];
    const float* convW[3]    = {(const float*)d_in[5], (const float*)d_in[7], (const float*)d_in[9]};
    const float* convB[3]    = {(const float*)d_in[6], (const float*)d_in[8], (const float*)d_in[10]};
    const float* poolP[3]    = {(const float*)d_in[11], (const float*)d_in[13], (const float*)d_in[15]};
    const float* poolBeta[3] = {(const float*)d_in[12], (const float*)d_in[14], (const float*)d_in[16]};
    const float* lin1W = (const float*)d_in[17];
    const float* lin1b = (const float*)d_in[18];
    const float* lin2W = (const float*)d_in[19];
    const float* lin2b = (const float*)d_in[20];
    float* out = (float*)d_out;

    char* w8 = (char*)d_ws;
    size_t off = 0;
    auto alloc = [&](size_t bytes)->char*{
        char* p = w8 + off; off += (bytes + 255) & ~(size_t)255; return p;
    };
    float* A     = (float*)alloc((size_t)65536*128*4);
    float* Bb    = (float*)alloc((size_t)65536*128*4);
    int*   srcA  = (int*)alloc((size_t)E_*4);
    int*   dstA  = (int*)alloc((size_t)E_*4);
    unsigned short* csr1 = (unsigned short*)alloc((size_t)65536*DEGMAX*2);
    unsigned short* csr2 = (unsigned short*)alloc((size_t)32768*DEGMAX*2);
    unsigned short* csr3 = (unsigned short*)alloc((size_t)16384*DEGMAX*2);
    int*   cntA  = (int*)alloc((size_t)(65536+32768+16384)*4);
    int*   cnt1 = cntA, *cnt2 = cntA + 65536, *cnt3 = cntA + 98304;
    int*   perm1 = (int*)alloc((size_t)65536*4);
    int*   perm2 = (int*)alloc((size_t)32768*4);
    int*   perm3 = (int*)alloc((size_t)16384*4);
    float* dinv1 = (float*)alloc((size_t)65536*4);
    float* dinv2 = (float*)alloc((size_t)32768*4);
    float* dinv3 = (float*)alloc((size_t)16384*4);
    float* score1 = (float*)alloc((size_t)65536*4);
    float* score2 = (float*)alloc((size_t)32768*4);
    int*   sel2  = (int*)alloc((size_t)32768*4);
    int*   sel3  = (int*)alloc((size_t)16384*4);
    float* th2   = (float*)alloc((size_t)32768*4);
    float* th3   = (float*)alloc((size_t)16384*4);

    // ----- prep1 (LDS CSR build) then lump GEMM (demerged for visibility) -----
    k_prep1<<<G_, 512, 0, stream>>>(ei, cnt1, csr1, perm1, dinv1);
    k_gemm_mfma<8><<<512, 512, 0, stream>>>(x, lumpW, lumpb, A,
            nullptr, nullptr, nullptr, nullptr);

    // ----- stage 1: conv1 (L=4, nper=512), pool -> 256/graph -----
    k_prop<512,4,4,false><<<dim3(G_,4), 1024, 0, stream>>>(perm1, dinv1, csr1, A,
            nullptr, nullptr, Bb);
    k_gemm_mfma<8><<<512, 512, 0, stream>>>(Bb, convW[0], convB[0], A,
            poolP[0], poolBeta[0], cnt1, score1);
    k_pooltop<512,true><<<G_, 512, 0, stream>>>(score1, ei, ei + E_, srcA, dstA,
            cnt2, csr2, perm2, dinv2, sel2, th2);

    // ----- stage 2: conv2 (L=2, nper=256), pool -> 128/graph -----
    k_prop<256,2,2,true><<<dim3(G_,4), 1024, 0, stream>>>(perm2, dinv2, csr2, A,
            sel2, th2, Bb);
    k_gemm_mfma<8><<<256, 512, 0, stream>>>(Bb, convW[1], convB[1], A,
            poolP[1], poolBeta[1], cnt2, score2);
    k_pooltop<256,true><<<G_, 512, 0, stream>>>(score2, srcA, dstA, srcA, dstA,
            cnt3, csr3, perm3, dinv3, sel3, th3);

    // ----- stage 3: conv3 (L=2, nper=128) then fused conv3-gemm+pool+mean+MLP -----
    k_prop<128,2,1,true><<<dim3(G_,4), 1024, 0, stream>>>(perm3, dinv3, csr3, A,
            sel3, th3, Bb);
    k_stage3<<<G_, 512, 0, stream>>>(Bb, convW[2], convB[2],
            poolP[2], poolBeta[2], cnt3, lin1W, lin1b, lin2W, lin2b, out);
}